// Round 7
// baseline (793.357 us; speedup 1.0000x reference)
//
#include <hip/hip_runtime.h>

typedef __bf16 bf16;
typedef bf16 bf16x8 __attribute__((ext_vector_type(8)));
typedef bf16 bf16x4 __attribute__((ext_vector_type(4)));
typedef bf16 bf16x2 __attribute__((ext_vector_type(2)));
typedef float floatx4 __attribute__((ext_vector_type(4)));

#define MFMA __builtin_amdgcn_mfma_f32_16x16x32_bf16

__device__ __forceinline__ float bfhi_f(unsigned u) {
  const unsigned x = u << 16;
  return __builtin_bit_cast(float, x);
}
__device__ __forceinline__ float bflo_f(unsigned u) {
  const unsigned x = u & 0xffff0000u;
  return __builtin_bit_cast(float, x);
}

// LDS-only barrier: waits for this wave's LDS ops (lgkmcnt) then syncs the
// block, WITHOUT the vmcnt(0) drain __syncthreads() emits. Global loads and
// stores stay in flight across it.
__device__ __forceinline__ void bar_lds() {
  asm volatile("s_waitcnt lgkmcnt(0)" ::: "memory");
  __builtin_amdgcn_s_barrier();
}

// ---------------- setup kernels ----------------

__global__ void hist_kernel(const int* __restrict__ ei, int* __restrict__ cnt, int E) {
  int e = blockIdx.x * blockDim.x + threadIdx.x;
  if (e < E) atomicAdd(&cnt[ei[E + e]], 1);
}

__global__ void gcnt_kernel(const int* __restrict__ batch, int* __restrict__ gcnt,
                            int N, int B) {
  const int b = threadIdx.x;
  if (b >= B) return;
  auto lb = [&](int v) {
    int lo = 0, hi = N;
    while (lo < hi) {
      const int mid = (lo + hi) >> 1;
      if (batch[mid] < v) lo = mid + 1; else hi = mid;
    }
    return lo;
  };
  gcnt[b] = lb(b + 1) - lb(b);
}

__global__ void scan1_kernel(const int* __restrict__ cnt, int* __restrict__ colptr,
                             int* __restrict__ rctr, int* __restrict__ btot, int n) {
  __shared__ int sd[256];
  const int tid = threadIdx.x;
  const int i0 = blockIdx.x * 2048 + tid * 8;
  int v[8];
  int tot = 0;
#pragma unroll
  for (int j = 0; j < 8; ++j) {
    const int i = i0 + j;
    v[j] = (i < n) ? cnt[i] : 0;
    tot += v[j];
  }
  sd[tid] = tot;
  __syncthreads();
  for (int off = 1; off < 256; off <<= 1) {
    const int t = (tid >= off) ? sd[tid - off] : 0;
    __syncthreads();
    sd[tid] += t;
    __syncthreads();
  }
  int excl = sd[tid] - tot;
#pragma unroll
  for (int j = 0; j < 8; ++j) {
    const int i = i0 + j;
    if (i < n) { colptr[i] = excl; rctr[i] = excl; }
    excl += v[j];
  }
  if (tid == 255) btot[blockIdx.x] = sd[255];
}

__global__ void scan2_kernel(int* __restrict__ colptr, int* __restrict__ rctr,
                             const int* __restrict__ btot, int n) {
  __shared__ int off_s;
  const int tid = threadIdx.x;
  if (blockIdx.x == 0) return;
  if (tid == 0) {
    int o = 0;
    for (int j = 0; j < (int)blockIdx.x; ++j) o += btot[j];
    off_s = o;
  }
  __syncthreads();
  const int off = off_s;
  const int i0 = blockIdx.x * 2048 + tid * 8;
#pragma unroll
  for (int j = 0; j < 8; ++j) {
    const int i = i0 + j;
    if (i < n) { colptr[i] += off; rctr[i] += off; }
  }
}

__global__ void place_kernel(const int* __restrict__ ei, int* __restrict__ rctr,
                             int* __restrict__ esrow, int E) {
  int e = blockIdx.x * blockDim.x + threadIdx.x;
  if (e >= E) return;
  const int r = ei[e];
  const int c = ei[E + e];
  const int p = atomicAdd(&rctr[c], 1);
  esrow[p] = r;
}

// transpose+split: src [L][Ksrc][H] fp32 (first K rows) -> dst [L][2][H][K] bf16
__global__ void wsplit_kernel(const float* __restrict__ src, bf16* __restrict__ dst,
                              int Ksrc, int K, int HH) {
  const int l = blockIdx.y;
  const int gid = blockIdx.x * blockDim.x + threadIdx.x;
  if (gid >= K * HH) return;
  const int h = gid / K, k = gid - h * K;
  const float v = src[(size_t)l * Ksrc * HH + (size_t)k * HH + h];
  const bf16 hi = (bf16)v;
  const bf16 lo = (bf16)(v - (float)hi);
  bf16* d = dst + (size_t)l * 2 * K * HH;
  d[(size_t)h * K + k] = hi;
  d[(size_t)K * HH + (size_t)h * K + k] = lo;
}

// Build fused node-GEMM1 weight G[l] (256x128 fp32):
//   rows   0..127 : x-part      = n2w1[l][0:128]
//   rows 128..255 : agg-part    = n1w2[l] @ n2w1[l][128:256]
// (aggregate-H1-before-W2 fusion: agg@W_a == aggH1 @ (W2e@W_a))
__global__ void wfuse_kernel(const float* __restrict__ n2w1,
                             const float* __restrict__ n1w2,
                             float* __restrict__ G) {
  const int l = blockIdx.y, k = blockIdx.x, h = threadIdx.x;
  const float* w = n2w1 + (size_t)l * 384 * 128;
  float* g = G + (size_t)l * 256 * 128;
  g[(size_t)k * 128 + h] = w[(size_t)k * 128 + h];
  const float* a = n1w2 + (size_t)l * 128 * 128 + (size_t)k * 128;
  float s = 0.f;
#pragma unroll 8
  for (int j = 0; j < 128; ++j)
    s = fmaf(a[j], w[(size_t)(128 + j) * 128 + h], s);
  g[(size_t)(128 + k) * 128 + h] = s;
}

__global__ void xsplit_kernel(const float* __restrict__ x, bf16* __restrict__ xhi,
                              bf16* __restrict__ xlo, int n4) {
  const int i = blockIdx.x * 256 + threadIdx.x;
  if (i >= n4) return;
  const float4 v = ((const float4*)x)[i];
  bf16x4 h, l;
  const float vv[4] = {v.x, v.y, v.z, v.w};
#pragma unroll
  for (int r = 0; r < 4; ++r) {
    h[r] = (bf16)vv[r];
    l[r] = (bf16)(vv[r] - (float)h[r]);
  }
  *(bf16x4*)&xhi[(size_t)i * 4] = h;
  *(bf16x4*)&xlo[(size_t)i * 4] = l;
}

// ---------------- layer-0 edge MLP: H1 = relu(x@W1e+b1e) only -------------
__global__ __launch_bounds__(256, 3)
void pnode_mfma(const bf16* __restrict__ xh, const bf16* __restrict__ xl,
                const bf16* __restrict__ w1t, const float* __restrict__ b1,
                bf16* __restrict__ P, int N) {
  __shared__ __align__(16) bf16 R[64 * 136];   // 17.4 KB hi-only staging

  const int tid = threadIdx.x;
  const int n0 = blockIdx.x * 64;
  const int wave = tid >> 6, lane = tid & 63, q = lane >> 4, lr = lane & 15;
  const int hbase = wave * 32;

  int nn[4];
#pragma unroll
  for (int nt = 0; nt < 4; ++nt) {
    int n = n0 + nt * 16 + lr;
    nn[nt] = (n > N - 1) ? (N - 1) : n;
  }

  const floatx4 zz = {0.f, 0.f, 0.f, 0.f};
  floatx4 acc[2][4];
#pragma unroll
  for (int mt = 0; mt < 2; ++mt)
#pragma unroll
    for (int nt = 0; nt < 4; ++nt) acc[mt][nt] = zz;

  // GEMM1: K=128, A and B double-buffered
  {
    bf16x8 bh[2][4], bl[2][4], ah[2][2], al[2][2];
    auto loadA = [&](int kc, int buf) {
#pragma unroll
      for (int mt = 0; mt < 2; ++mt) {
        const bf16* wp = w1t + (size_t)(hbase + mt * 16 + lr) * 128 + kc * 32 + q * 8;
        ah[buf][mt] = *(const bf16x8*)wp;
        al[buf][mt] = *(const bf16x8*)(wp + 16384);
      }
    };
    auto loadB = [&](int kc, int buf) {
#pragma unroll
      for (int nt = 0; nt < 4; ++nt) {
        const size_t off = (size_t)nn[nt] * 128 + kc * 32 + q * 8;
        bh[buf][nt] = *(const bf16x8*)(xh + off);
        bl[buf][nt] = *(const bf16x8*)(xl + off);
      }
    };
    loadA(0, 0);
    loadB(0, 0);
#pragma unroll
    for (int kc = 0; kc < 4; ++kc) {
      const int cur = kc & 1, nxt = cur ^ 1;
      if (kc < 3) {
        loadA(kc + 1, nxt);
        loadB(kc + 1, nxt);
      }
#pragma unroll
      for (int nt = 0; nt < 4; ++nt)
#pragma unroll
        for (int mt = 0; mt < 2; ++mt) {
          acc[mt][nt] = MFMA(ah[cur][mt], bh[cur][nt], acc[mt][nt], 0, 0, 0);
          acc[mt][nt] = MFMA(al[cur][mt], bh[cur][nt], acc[mt][nt], 0, 0, 0);
          acc[mt][nt] = MFMA(ah[cur][mt], bl[cur][nt], acc[mt][nt], 0, 0, 0);
        }
    }
  }

  // epilogue: bias+relu -> H1 hi bf16, stage + coalesced store
#pragma unroll
  for (int mt = 0; mt < 2; ++mt) {
    const int h0 = hbase + mt * 16 + q * 4;
    const float* bp = &b1[h0];
#pragma unroll
    for (int nt = 0; nt < 4; ++nt) {
      const int e = nt * 16 + lr;
      bf16x4 hh;
#pragma unroll
      for (int r = 0; r < 4; ++r)
        hh[r] = (bf16)fmaxf(acc[mt][nt][r] + bp[r], 0.f);
      *(bf16x4*)&R[e * 136 + h0] = hh;
    }
  }
  bar_lds();
#pragma unroll
  for (int it = 0; it < 4; ++it) {
    const int idx = it * 256 + tid;
    const int row = idx >> 4;
    const int f8 = (idx & 15) * 8;
    const int n = n0 + row;
    if (n < N)
      *(bf16x8*)&P[(size_t)n * 128 + f8] = *(const bf16x8*)&R[row * 136 + f8];
  }
}

// ---------------- global-MLP body (shared by fused + standalone) ----------
__device__ __forceinline__ void gmlp_dev(
    int b, int t, const float* __restrict__ uin, float* __restrict__ gx,
    const int* __restrict__ gcnt,
    const float* __restrict__ gw1, const float* __restrict__ gb1,
    const float* __restrict__ gw2, const float* __restrict__ gb2,
    float* __restrict__ uout,
    const float* __restrict__ w1n, const float* __restrict__ b1n,
    const float* __restrict__ pbn, float* __restrict__ UW, int has_next) {
  __shared__ float g[256];
  __shared__ float g1[128];
  const bool act = t < 128;
  const int c = gcnt[b];
  const float inv = 1.f / (float)(c > 1 ? c : 1);
  if (act) {
    g[t] = uin[b * 128 + t];
    g[128 + t] = gx[b * 128 + t] * inv;
    gx[b * 128 + t] = 0.f;
  }
  __syncthreads();
  float acc = 0.f;
  if (act) {
    acc = gb1[t];
#pragma unroll 8
    for (int k = 0; k < 256; ++k) acc = fmaf(g[k], gw1[k * 128 + t], acc);
    g1[t] = fmaxf(acc, 0.f);
  }
  __syncthreads();
  float acc2 = 0.f;
  if (act) {
    acc2 = gb2[t];
#pragma unroll 8
    for (int k = 0; k < 128; ++k) acc2 = fmaf(g1[k], gw2[k * 128 + t], acc2);
    uout[b * 128 + t] = acc2;
  }
  if (has_next) {
    __syncthreads();
    if (act) g[t] = acc2;
    __syncthreads();
    if (act) {
      float s = b1n[t];
#pragma unroll 8
      for (int k = 0; k < 128; ++k)
        s = fmaf(g[k], w1n[(size_t)(256 + k) * 128 + t], s);
#pragma unroll 8
      for (int k = 0; k < 128; ++k)
        s = fmaf(pbn[k], w1n[(size_t)(128 + k) * 128 + t], s);
      UW[b * 128 + t] = s;
    }
  }
}

// ---------------- CSR mean-aggregate + optional fused gmlp tail ----------
// Blocks [0, nAgg) aggregate H1; blocks [nAgg, nAgg+B) run the previous
// layer's global MLP concurrently (both depend only on the preceding
// node_p; hides gmlp's serial latency under the aggregate).
__global__ __launch_bounds__(256, 8)
void agg_csr(const bf16* __restrict__ P, const int* __restrict__ colptr,
             const int* __restrict__ esrow,
             bf16* __restrict__ aggh, bf16* __restrict__ aggl, int N, int E,
             int nAgg,
             const float* __restrict__ uin, float* __restrict__ gx,
             const int* __restrict__ gcnt,
             const float* __restrict__ gw1, const float* __restrict__ gb1,
             const float* __restrict__ gw2, const float* __restrict__ gb2,
             float* __restrict__ uout,
             const float* __restrict__ w1n, const float* __restrict__ b1n,
             const float* __restrict__ pbn, float* __restrict__ UW) {
  if ((int)blockIdx.x >= nAgg) {
    gmlp_dev(blockIdx.x - nAgg, threadIdx.x, uin, gx, gcnt, gw1, gb1, gw2, gb2,
             uout, w1n, b1n, pbn, UW, 1);
    return;
  }
  const int lane = threadIdx.x & 63;
  const int c = blockIdx.x * 4 + (threadIdx.x >> 6);
  if (c >= N) return;
  const int beg = colptr[c];
  const int end = (c == N - 1) ? E : colptr[c + 1];
  float s0[4] = {0.f, 0.f, 0.f, 0.f};
  float s1[4] = {0.f, 0.f, 0.f, 0.f};
  int e = beg;
  for (; e + 8 <= end; e += 8) {
    int r[8];
#pragma unroll
    for (int j = 0; j < 8; ++j) r[j] = esrow[e + j];
    unsigned v[8];
#pragma unroll
    for (int j = 0; j < 8; ++j)
      v[j] = *(const unsigned*)&P[(size_t)r[j] * 128 + lane * 2];
#pragma unroll
    for (int j = 0; j < 8; ++j) {
      s0[j & 3] += bfhi_f(v[j]);
      s1[j & 3] += bflo_f(v[j]);
    }
  }
  const int rem = end - e;
  if (rem > 0) {
    int r[8];
#pragma unroll
    for (int j = 0; j < 8; ++j) r[j] = esrow[e + (j < rem ? j : 0)];
    unsigned v[8];
#pragma unroll
    for (int j = 0; j < 8; ++j)
      v[j] = *(const unsigned*)&P[(size_t)r[j] * 128 + lane * 2];
#pragma unroll
    for (int j = 0; j < 8; ++j) {
      if (j < rem) {
        s0[j & 3] += bfhi_f(v[j]);
        s1[j & 3] += bflo_f(v[j]);
      }
    }
  }
  const int cc = end - beg;
  const float inv = 1.f / (float)(cc > 1 ? cc : 1);
  const float v0 = ((s0[0] + s0[1]) + (s0[2] + s0[3])) * inv;
  const float v1 = ((s1[0] + s1[1]) + (s1[2] + s1[3])) * inv;
  bf16x2 h, l;
  h[0] = (bf16)v0;  l[0] = (bf16)(v0 - (float)h[0]);
  h[1] = (bf16)v1;  l[1] = (bf16)(v1 - (float)h[1]);
  *(bf16x2*)&aggh[(size_t)c * 128 + lane * 2] = h;
  *(bf16x2*)&aggl[(size_t)c * 128 + lane * 2] = l;
}

// ---------------- fused node MLP + gsum + next-layer H1 (8-wave TLP) ------
// 512 threads / 8 waves per 64-node tile; each wave owns 16 output cols.
// Same per-block weight traffic as the 4-wave version (A rows read once per
// block), B loads duplicated 8x (L2-served). Doubles resident waves/CU for
// latency hiding: the diagnosed bottleneck is TLP starvation, not ILP.
__global__ __launch_bounds__(512, 4)
void node_p(bf16* xh, bf16* xl,
            const bf16* __restrict__ aggh, const bf16* __restrict__ aggl,
            const float* __restrict__ UW, const int* __restrict__ batch,
            const bf16* __restrict__ w1t, const bf16* __restrict__ w2t,
            const float* __restrict__ b2,
            const bf16* __restrict__ w1te, const float* __restrict__ b1e,
            bf16* __restrict__ Pout, float* __restrict__ gx,
            float* __restrict__ xout, int write_x, int has_next, int N) {
  __shared__ __align__(16) bf16 R[2 * 64 * 136];   // 34.8 KB, time-shared
  __shared__ int sbatch[64];

  const int tid = threadIdx.x;
  const int n0 = blockIdx.x * 64;
  const int wave = tid >> 6, lane = tid & 63, q = lane >> 4, lr = lane & 15;
  const int hbase = wave * 16;     // 8 waves x 16 output cols

  if (tid < 64) {
    int n = n0 + tid;
    sbatch[tid] = batch[(n > N - 1) ? (N - 1) : n];
  }

  int nn[4], ub[4];
#pragma unroll
  for (int nt = 0; nt < 4; ++nt) {
    int n = n0 + nt * 16 + lr;
    if (n > N - 1) n = N - 1;
    nn[nt] = n;
    ub[nt] = batch[n];
  }

  floatx4 acc[4];
#pragma unroll
  for (int nt = 0; nt < 4; ++nt)
    acc[nt] = *(const floatx4*)&UW[(size_t)ub[nt] * 128 + hbase + q * 4];

  // GEMM1: K=256 (x hi/lo | aggH1 hi/lo vs fused weight)
  {
    bf16x8 bh[2][4], bl[2][4], ah[2], al[2];
    auto loadB = [&](int kc, int buf) {
#pragma unroll
      for (int nt = 0; nt < 4; ++nt) {
        if (kc < 4) {
          const size_t off = (size_t)nn[nt] * 128 + kc * 32 + q * 8;
          bh[buf][nt] = *(const bf16x8*)(xh + off);
          bl[buf][nt] = *(const bf16x8*)(xl + off);
        } else {
          const size_t off = (size_t)nn[nt] * 128 + (kc - 4) * 32 + q * 8;
          bh[buf][nt] = *(const bf16x8*)(aggh + off);
          bl[buf][nt] = *(const bf16x8*)(aggl + off);
        }
      }
    };
    auto loadA = [&](int kc, int buf) {
      const bf16* wp = w1t + (size_t)(hbase + lr) * 256 + kc * 32 + q * 8;
      ah[buf] = *(const bf16x8*)wp;
      al[buf] = *(const bf16x8*)(wp + 32768);
    };
    loadA(0, 0);
    loadB(0, 0);
#pragma unroll
    for (int kc = 0; kc < 8; ++kc) {
      const int cur = kc & 1, nxt = cur ^ 1;
      if (kc < 7) {
        loadA(kc + 1, nxt);
        loadB(kc + 1, nxt);
      }
#pragma unroll
      for (int nt = 0; nt < 4; ++nt) {
        acc[nt] = MFMA(ah[cur], bh[cur][nt], acc[nt], 0, 0, 0);
        acc[nt] = MFMA(al[cur], bh[cur][nt], acc[nt], 0, 0, 0);
        acc[nt] = MFMA(ah[cur], bl[cur][nt], acc[nt], 0, 0, 0);
      }
    }
  }

  // prefetch GEMM2 ks=0 A-frags
  bf16x8 a2h[2], a2l[2];
  {
    const bf16* wp = w2t + (size_t)(hbase + lr) * 128 + q * 8;
    a2h[0] = *(const bf16x8*)wp;
    a2l[0] = *(const bf16x8*)(wp + 16384);
  }

  // epilogue 1: relu (b1 folded in UW) -> H1 hi/lo
  const floatx4 zz = {0.f, 0.f, 0.f, 0.f};
  const int h0 = hbase + q * 4;
#pragma unroll
  for (int nt = 0; nt < 4; ++nt) {
    const int e = nt * 16 + lr;
    bf16x4 hh, ll;
#pragma unroll
    for (int r = 0; r < 4; ++r) {
      const float v = fmaxf(acc[nt][r], 0.f);
      hh[r] = (bf16)v;
      ll[r] = (bf16)(v - (float)hh[r]);
    }
    *(bf16x4*)&R[e * 136 + h0] = hh;
    *(bf16x4*)&R[64 * 136 + e * 136 + h0] = ll;
    acc[nt] = zz;
  }
  bar_lds();

  // GEMM2: A from global (rows hbase..hbase+16), B (H1) from LDS
#pragma unroll
  for (int ks = 0; ks < 4; ++ks) {
    const int cur = ks & 1, nxt = cur ^ 1;
    if (ks < 3) {
      const bf16* wp = w2t + (size_t)(hbase + lr) * 128 + (ks + 1) * 32 + q * 8;
      a2h[nxt] = *(const bf16x8*)wp;
      a2l[nxt] = *(const bf16x8*)(wp + 16384);
    }
    bf16x8 b2h[4], b2l[4];
#pragma unroll
    for (int nt = 0; nt < 4; ++nt) {
      const bf16* hp = &R[(nt * 16 + lr) * 136 + ks * 32 + q * 8];
      b2h[nt] = *(const bf16x8*)hp;
      b2l[nt] = *(const bf16x8*)(hp + 64 * 136);
    }
#pragma unroll
    for (int nt = 0; nt < 4; ++nt) {
      acc[nt] = MFMA(a2h[cur], b2h[nt], acc[nt], 0, 0, 0);
      acc[nt] = MFMA(a2l[cur], b2h[nt], acc[nt], 0, 0, 0);
      acc[nt] = MFMA(a2h[cur], b2l[nt], acc[nt], 0, 0, 0);
    }
  }
  bar_lds();   // H1 reads done; Xt fp32 [64][132] overlays R

  // prefetch H1p-GEMM kc=0 A-frags
  bf16x8 pah[2], pal[2];
  if (has_next) {
    const bf16* wp = w1te + (size_t)(hbase + lr) * 128 + q * 8;
    pah[0] = *(const bf16x8*)wp;
    pal[0] = *(const bf16x8*)(wp + 16384);
  }

  // epilogue 2: +b2 -> Xt
  float* Xt = (float*)&R[0];
  {
    const float* bp = &b2[h0];
#pragma unroll
    for (int nt = 0; nt < 4; ++nt) {
      const int e = nt * 16 + lr;
      const int n = n0 + e;
      float4 o;
      o.x = (n < N) ? acc[nt][0] + bp[0] : 0.f;
      o.y = (n < N) ? acc[nt][1] + bp[1] : 0.f;
      o.z = (n < N) ? acc[nt][2] + bp[2] : 0.f;
      o.w = (n < N) ? acc[nt][3] + bp[3] : 0.f;
      *(float4*)&Xt[e * 132 + h0] = o;
    }
  }
  bar_lds();

  // coalesced xh/xl stores (next layer), optional xout  (512 threads)
  if (has_next) {
#pragma unroll
    for (int it = 0; it < 2; ++it) {
      const int idx = it * 512 + tid;
      const int row = idx >> 4;
      const int f8 = (idx & 15) * 8;
      const int n = n0 + row;
      if (n < N) {
        bf16x8 hh, ll;
#pragma unroll
        for (int j = 0; j < 8; ++j) {
          const float v = Xt[row * 132 + f8 + j];
          hh[j] = (bf16)v;
          ll[j] = (bf16)(v - (float)hh[j]);
        }
        *(bf16x8*)&xh[(size_t)n * 128 + f8] = hh;
        *(bf16x8*)&xl[(size_t)n * 128 + f8] = ll;
      }
    }
  }
  if (write_x) {
#pragma unroll
    for (int it = 0; it < 4; ++it) {
      const int idx = it * 512 + tid;
      const int row = idx >> 5;
      const int f4 = (idx & 31) * 4;
      const int n = n0 + row;
      if (n < N)
        *(float4*)&xout[(size_t)n * 128 + f4] = *(const float4*)&Xt[row * 132 + f4];
    }
  }

  // fused gsum: 4 groups x 16 sorted-batch rows (512 threads)
  {
    const int f = tid & 127;
    const int es = (tid >> 7) * 16;
    int cur = sbatch[es];
    float s = 0.f;
    for (int e = es; e < es + 16; ++e) {
      const int b = sbatch[e];
      const float v = Xt[e * 132 + f];
      if (b != cur) {
        atomicAdd(&gx[(size_t)cur * 128 + f], s);
        s = 0.f;
        cur = b;
      }
      s += v;
    }
    atomicAdd(&gx[(size_t)cur * 128 + f], s);
  }

  if (!has_next) return;

  // H1p phase: Pout = relu(Xnew@W1e + b1e) (hi bf16) — W2e fused downstream
  floatx4 pacc[4];
#pragma unroll
  for (int nt = 0; nt < 4; ++nt) pacc[nt] = zz;

#pragma unroll
  for (int kc = 0; kc < 4; ++kc) {
    const int cur = kc & 1, nxt = cur ^ 1;
    if (kc < 3) {
      const bf16* wp = w1te + (size_t)(hbase + lr) * 128 + (kc + 1) * 32 + q * 8;
      pah[nxt] = *(const bf16x8*)wp;
      pal[nxt] = *(const bf16x8*)(wp + 16384);
    }
    bf16x8 bh[4], bl[4];
#pragma unroll
    for (int nt = 0; nt < 4; ++nt) {
      const float* xp = &Xt[(nt * 16 + lr) * 132 + kc * 32 + q * 8];
#pragma unroll
      for (int r = 0; r < 8; ++r) {
        const float v = xp[r];
        bh[nt][r] = (bf16)v;
        bl[nt][r] = (bf16)(v - (float)bh[nt][r]);
      }
    }
#pragma unroll
    for (int nt = 0; nt < 4; ++nt) {
      pacc[nt] = MFMA(pah[cur], bh[nt], pacc[nt], 0, 0, 0);
      pacc[nt] = MFMA(pal[cur], bh[nt], pacc[nt], 0, 0, 0);
      pacc[nt] = MFMA(pah[cur], bl[nt], pacc[nt], 0, 0, 0);
    }
  }
  bar_lds();   // Xt reads (incl. gsum) done; H1p hi staging overlays R

  // epilogue: +b1e, relu -> hi bf16 stage, coalesced store
  {
    const float* bp = &b1e[h0];
#pragma unroll
    for (int nt = 0; nt < 4; ++nt) {
      const int e = nt * 16 + lr;
      bf16x4 hh;
#pragma unroll
      for (int r = 0; r < 4; ++r)
        hh[r] = (bf16)fmaxf(pacc[nt][r] + bp[r], 0.f);
      *(bf16x4*)&R[e * 136 + h0] = hh;
    }
  }
  bar_lds();
#pragma unroll
  for (int it = 0; it < 2; ++it) {
    const int idx = it * 512 + tid;
    const int row = idx >> 4;
    const int f8 = (idx & 15) * 8;
    const int n = n0 + row;
    if (n < N)
      *(bf16x8*)&Pout[(size_t)n * 128 + f8] = *(const bf16x8*)&R[row * 136 + f8];
  }
}

// ---------------- UW = u @ W1c + b1 + b2e @ W1a (layer 0) ----------------
__global__ void uw_kernel(const float* __restrict__ u, const float* __restrict__ w1,
                          const float* __restrict__ b1, const float* __restrict__ pb,
                          float* __restrict__ UW) {
  const int b = blockIdx.x, h = threadIdx.x;
  float s = b1[h];
#pragma unroll 8
  for (int k = 0; k < 128; ++k)
    s = fmaf(u[b * 128 + k], w1[(size_t)(256 + k) * 128 + h], s);
#pragma unroll 8
  for (int k = 0; k < 128; ++k)
    s = fmaf(pb[k], w1[(size_t)(128 + k) * 128 + h], s);
  UW[b * 128 + h] = s;
}

// ---------------- standalone global MLP (last layer only) ----------------
__global__ __launch_bounds__(128)
void gmlp_kernel(const float* __restrict__ uin, float* __restrict__ gx,
                 const int* __restrict__ gcnt,
                 const float* __restrict__ gw1, const float* __restrict__ gb1,
                 const float* __restrict__ gw2, const float* __restrict__ gb2,
                 float* __restrict__ uout,
                 const float* __restrict__ w1n, const float* __restrict__ b1n,
                 const float* __restrict__ pbn, float* __restrict__ UW,
                 int has_next) {
  gmlp_dev(blockIdx.x, threadIdx.x, uin, gx, gcnt, gw1, gb1, gw2, gb2,
           uout, w1n, b1n, pbn, UW, has_next);
}

// ---------------- host ----------------
extern "C" void kernel_launch(void* const* d_in, const int* in_sizes, int n_in,
                              void* d_out, int out_size, void* d_ws, size_t ws_size,
                              hipStream_t stream) {
  constexpr int N = 50000, E = 600000, B = 64, F = 128, L = 4;

  const float* x0    = (const float*)d_in[0];
  const int*   ei    = (const int*)  d_in[1];
  const float* u0    = (const float*)d_in[2];
  const int*   batch = (const int*)  d_in[3];
  const float* n1w1  = (const float*)d_in[4];
  const float* n1b1  = (const float*)d_in[5];
  const float* n1w2  = (const float*)d_in[6];
  const float* n1b2  = (const float*)d_in[7];
  const float* n2w1  = (const float*)d_in[8];
  const float* n2b1  = (const float*)d_in[9];
  const float* n2w2  = (const float*)d_in[10];
  const float* n2b2  = (const float*)d_in[11];
  const float* gw1   = (const float*)d_in[12];
  const float* gb1   = (const float*)d_in[13];
  const float* gw2   = (const float*)d_in[14];
  const float* gb2   = (const float*)d_in[15];
  float* out = (float*)d_out;

  char* p = (char*)d_ws;
  auto carve = [&](size_t bytes) -> void* {
    void* q = (void*)p;
    p += (bytes + 255) & ~(size_t)255;
    return q;
  };
  float* ubuf  = (float*)carve((size_t)B * F * 4);
  float* gx    = (float*)carve((size_t)B * F * 4);
  float* UW    = (float*)carve((size_t)B * F * 4);
  int*   cnt   = (int*)carve((size_t)N * 4);
  int*   colptr= (int*)carve((size_t)(N + 1) * 4);
  int*   rctr  = (int*)carve((size_t)N * 4);
  int*   gcnt  = (int*)carve((size_t)B * 4);
  int*   btot  = (int*)carve(32 * 4);
  int*   esrow = (int*)carve((size_t)E * 4);
  bf16*  xhi   = (bf16*)carve((size_t)N * F * 2);
  bf16*  xlo   = (bf16*)carve((size_t)N * F * 2);
  bf16*  P_a   = (bf16*)carve((size_t)N * F * 2);
  bf16*  P_b   = (bf16*)carve((size_t)N * F * 2);
  bf16*  aggh  = (bf16*)carve((size_t)N * F * 2);
  bf16*  aggl  = (bf16*)carve((size_t)N * F * 2);
  bf16*  w1t_e = (bf16*)carve((size_t)L * 2 * 128 * 128 * 2);
  bf16*  w1t_n = (bf16*)carve((size_t)L * 2 * 256 * 128 * 2);
  bf16*  w2t_n = (bf16*)carve((size_t)L * 2 * 128 * 128 * 2);
  float* wtmp  = (float*)carve((size_t)L * 256 * 128 * 4);

  constexpr int SCAN_BLOCKS = (N + 2047) / 2048;

  hipMemsetAsync(cnt, 0, (size_t)N * 4, stream);
  hipMemsetAsync(gx, 0, (size_t)B * F * 4, stream);   // re-zeroed by gmlp
  hist_kernel<<<(E + 255) / 256, 256, 0, stream>>>(ei, cnt, E);
  gcnt_kernel<<<1, 64, 0, stream>>>(batch, gcnt, N, B);
  scan1_kernel<<<SCAN_BLOCKS, 256, 0, stream>>>(cnt, colptr, rctr, btot, N);
  scan2_kernel<<<SCAN_BLOCKS, 256, 0, stream>>>(colptr, rctr, btot, N);
  place_kernel<<<(E + 255) / 256, 256, 0, stream>>>(ei, rctr, esrow, E);
  wsplit_kernel<<<dim3(64, L), 256, 0, stream>>>(n1w1, w1t_e, 128, 128, 128);
  wfuse_kernel<<<dim3(128, L), 128, 0, stream>>>(n2w1, n1w2, wtmp);
  wsplit_kernel<<<dim3(128, L), 256, 0, stream>>>(wtmp, w1t_n, 256, 256, 128);
  wsplit_kernel<<<dim3(64, L), 256, 0, stream>>>(n2w2, w2t_n, 128, 128, 128);
  xsplit_kernel<<<(N * F / 4 + 255) / 256, 256, 0, stream>>>(x0, xhi, xlo, N * F / 4);
  uw_kernel<<<B, 128, 0, stream>>>(u0, n2w1, n2b1, n1b2, UW);

  const int NB = (N + 63) / 64;
  const int NAGG = (N + 3) / 4;
  pnode_mfma<<<NB, 256, 0, stream>>>(xhi, xlo, w1t_e, n1b1, P_a, N);

  // layer-0 aggregate (no gmlp to fuse yet)
  agg_csr<<<NAGG, 256, 0, stream>>>(P_a, colptr, esrow, aggh, aggl, N, E, NAGG,
      u0, gx, gcnt, gw1, gb1, gw2, gb2, ubuf, n2w1, n2b1, n1b2, UW);

  for (int l = 0; l < L; ++l) {
    const int    wx   = (l == L - 1) ? 1 : 0;
    const int    hn   = (l < L - 1) ? 1 : 0;
    bf16*        Pout = (l & 1) ? P_a : P_b;
    const int    le   = hn ? (l + 1) : l;

    node_p<<<NB, 512, 0, stream>>>(
        xhi, xlo, aggh, aggl, UW, batch,
        w1t_n + (size_t)l * 65536, w2t_n + (size_t)l * 32768,
        n2b2 + l * 128,
        w1t_e + (size_t)le * 32768, n1b1 + le * 128,
        Pout, gx, out, wx, hn, N);

    if (l < L - 1) {
      // aggregate for layer l+1, with this layer's gmlp fused in as B blocks
      agg_csr<<<NAGG + B, 256, 0, stream>>>(
          Pout, colptr, esrow, aggh, aggl, N, E, NAGG,
          (l ? ubuf : u0), gx, gcnt,
          gw1 + (size_t)l * 256 * 128, gb1 + l * 128,
          gw2 + (size_t)l * 128 * 128, gb2 + l * 128,
          ubuf,
          n2w1 + (size_t)(l + 1) * 384 * 128, n2b1 + (l + 1) * 128,
          n1b2 + (l + 1) * 128, UW);
    } else {
      gmlp_kernel<<<B, 128, 0, stream>>>(
          ubuf, gx, gcnt,
          gw1 + (size_t)l * 256 * 128, gb1 + l * 128,
          gw2 + (size_t)l * 128 * 128, gb2 + l * 128,
          out + (size_t)N * F,
          n2w1, n2b1, n1b2, UW, 0);
    }
  }
}

// Round 8
// 701.509 us; speedup vs baseline: 1.1309x; 1.1309x over previous
//
#include <hip/hip_runtime.h>

typedef __bf16 bf16;
typedef bf16 bf16x8 __attribute__((ext_vector_type(8)));
typedef bf16 bf16x4 __attribute__((ext_vector_type(4)));
typedef bf16 bf16x2 __attribute__((ext_vector_type(2)));
typedef float floatx4 __attribute__((ext_vector_type(4)));

#define MFMA __builtin_amdgcn_mfma_f32_16x16x32_bf16

__device__ __forceinline__ float bfhi_f(unsigned u) {
  const unsigned x = u << 16;
  return __builtin_bit_cast(float, x);
}
__device__ __forceinline__ float bflo_f(unsigned u) {
  const unsigned x = u & 0xffff0000u;
  return __builtin_bit_cast(float, x);
}

// LDS-only barrier: waits for this wave's LDS ops (lgkmcnt) then syncs the
// block, WITHOUT the vmcnt(0) drain __syncthreads() emits.
__device__ __forceinline__ void bar_lds() {
  asm volatile("s_waitcnt lgkmcnt(0)" ::: "memory");
  __builtin_amdgcn_s_barrier();
}

// ---------------- setup kernels ----------------

__global__ void hist_kernel(const int* __restrict__ ei, int* __restrict__ cnt, int E) {
  int e = blockIdx.x * blockDim.x + threadIdx.x;
  if (e < E) atomicAdd(&cnt[ei[E + e]], 1);
}

__global__ void gcnt_kernel(const int* __restrict__ batch, int* __restrict__ gcnt,
                            int N, int B) {
  const int b = threadIdx.x;
  if (b >= B) return;
  auto lb = [&](int v) {
    int lo = 0, hi = N;
    while (lo < hi) {
      const int mid = (lo + hi) >> 1;
      if (batch[mid] < v) lo = mid + 1; else hi = mid;
    }
    return lo;
  };
  gcnt[b] = lb(b + 1) - lb(b);
}

__global__ void scan1_kernel(const int* __restrict__ cnt, int* __restrict__ colptr,
                             int* __restrict__ rctr, int* __restrict__ btot, int n) {
  __shared__ int sd[256];
  const int tid = threadIdx.x;
  const int i0 = blockIdx.x * 2048 + tid * 8;
  int v[8];
  int tot = 0;
#pragma unroll
  for (int j = 0; j < 8; ++j) {
    const int i = i0 + j;
    v[j] = (i < n) ? cnt[i] : 0;
    tot += v[j];
  }
  sd[tid] = tot;
  __syncthreads();
  for (int off = 1; off < 256; off <<= 1) {
    const int t = (tid >= off) ? sd[tid - off] : 0;
    __syncthreads();
    sd[tid] += t;
    __syncthreads();
  }
  int excl = sd[tid] - tot;
#pragma unroll
  for (int j = 0; j < 8; ++j) {
    const int i = i0 + j;
    if (i < n) { colptr[i] = excl; rctr[i] = excl; }
    excl += v[j];
  }
  if (tid == 255) btot[blockIdx.x] = sd[255];
}

__global__ void scan2_kernel(int* __restrict__ colptr, int* __restrict__ rctr,
                             const int* __restrict__ btot, int n) {
  __shared__ int off_s;
  const int tid = threadIdx.x;
  if (blockIdx.x == 0) return;
  if (tid == 0) {
    int o = 0;
    for (int j = 0; j < (int)blockIdx.x; ++j) o += btot[j];
    off_s = o;
  }
  __syncthreads();
  const int off = off_s;
  const int i0 = blockIdx.x * 2048 + tid * 8;
#pragma unroll
  for (int j = 0; j < 8; ++j) {
    const int i = i0 + j;
    if (i < n) { colptr[i] += off; rctr[i] += off; }
  }
}

__global__ void place_kernel(const int* __restrict__ ei, int* __restrict__ rctr,
                             int* __restrict__ esrow, int E) {
  int e = blockIdx.x * blockDim.x + threadIdx.x;
  if (e >= E) return;
  const int r = ei[e];
  const int c = ei[E + e];
  const int p = atomicAdd(&rctr[c], 1);
  esrow[p] = r;
}

// transpose+split: src [L][Ksrc][H] fp32 (first K rows) -> dst [L][2][H][K] bf16
__global__ void wsplit_kernel(const float* __restrict__ src, bf16* __restrict__ dst,
                              int Ksrc, int K, int HH) {
  const int l = blockIdx.y;
  const int gid = blockIdx.x * blockDim.x + threadIdx.x;
  if (gid >= K * HH) return;
  const int h = gid / K, k = gid - h * K;
  const float v = src[(size_t)l * Ksrc * HH + (size_t)k * HH + h];
  const bf16 hi = (bf16)v;
  const bf16 lo = (bf16)(v - (float)hi);
  bf16* d = dst + (size_t)l * 2 * K * HH;
  d[(size_t)h * K + k] = hi;
  d[(size_t)K * HH + (size_t)h * K + k] = lo;
}

// Build fused node-GEMM1 weight G[l] (256x128 fp32):
//   rows   0..127 : x-part      = n2w1[l][0:128]
//   rows 128..255 : agg-part    = n1w2[l] @ n2w1[l][128:256]
__global__ void wfuse_kernel(const float* __restrict__ n2w1,
                             const float* __restrict__ n1w2,
                             float* __restrict__ G) {
  const int l = blockIdx.y, k = blockIdx.x, h = threadIdx.x;
  const float* w = n2w1 + (size_t)l * 384 * 128;
  float* g = G + (size_t)l * 256 * 128;
  g[(size_t)k * 128 + h] = w[(size_t)k * 128 + h];
  const float* a = n1w2 + (size_t)l * 128 * 128 + (size_t)k * 128;
  float s = 0.f;
#pragma unroll 8
  for (int j = 0; j < 128; ++j)
    s = fmaf(a[j], w[(size_t)(128 + j) * 128 + h], s);
  g[(size_t)(128 + k) * 128 + h] = s;
}

__global__ void xsplit_kernel(const float* __restrict__ x, bf16* __restrict__ xhi,
                              bf16* __restrict__ xlo, int n4) {
  const int i = blockIdx.x * 256 + threadIdx.x;
  if (i >= n4) return;
  const float4 v = ((const float4*)x)[i];
  bf16x4 h, l;
  const float vv[4] = {v.x, v.y, v.z, v.w};
#pragma unroll
  for (int r = 0; r < 4; ++r) {
    h[r] = (bf16)vv[r];
    l[r] = (bf16)(vv[r] - (float)h[r]);
  }
  *(bf16x4*)&xhi[(size_t)i * 4] = h;
  *(bf16x4*)&xlo[(size_t)i * 4] = l;
}

// ---------------- layer-0 edge MLP: H1 = relu(x@W1e+b1e) only -------------
__global__ __launch_bounds__(256, 3)
void pnode_mfma(const bf16* __restrict__ xh, const bf16* __restrict__ xl,
                const bf16* __restrict__ w1t, const float* __restrict__ b1,
                bf16* __restrict__ P, int N) {
  __shared__ __align__(16) bf16 R[64 * 136];   // 17.4 KB hi-only staging

  const int tid = threadIdx.x;
  const int n0 = blockIdx.x * 64;
  const int wave = tid >> 6, lane = tid & 63, q = lane >> 4, lr = lane & 15;
  const int hbase = wave * 32;

  int nn[4];
#pragma unroll
  for (int nt = 0; nt < 4; ++nt) {
    int n = n0 + nt * 16 + lr;
    nn[nt] = (n > N - 1) ? (N - 1) : n;
  }

  const floatx4 zz = {0.f, 0.f, 0.f, 0.f};
  floatx4 acc[2][4];
#pragma unroll
  for (int mt = 0; mt < 2; ++mt)
#pragma unroll
    for (int nt = 0; nt < 4; ++nt) acc[mt][nt] = zz;

  // GEMM1: K=128, A and B double-buffered
  {
    bf16x8 bh[2][4], bl[2][4], ah[2][2], al[2][2];
    auto loadA = [&](int kc, int buf) {
#pragma unroll
      for (int mt = 0; mt < 2; ++mt) {
        const bf16* wp = w1t + (size_t)(hbase + mt * 16 + lr) * 128 + kc * 32 + q * 8;
        ah[buf][mt] = *(const bf16x8*)wp;
        al[buf][mt] = *(const bf16x8*)(wp + 16384);
      }
    };
    auto loadB = [&](int kc, int buf) {
#pragma unroll
      for (int nt = 0; nt < 4; ++nt) {
        const size_t off = (size_t)nn[nt] * 128 + kc * 32 + q * 8;
        bh[buf][nt] = *(const bf16x8*)(xh + off);
        bl[buf][nt] = *(const bf16x8*)(xl + off);
      }
    };
    loadA(0, 0);
    loadB(0, 0);
#pragma unroll
    for (int kc = 0; kc < 4; ++kc) {
      const int cur = kc & 1, nxt = cur ^ 1;
      if (kc < 3) {
        loadA(kc + 1, nxt);
        loadB(kc + 1, nxt);
      }
#pragma unroll
      for (int nt = 0; nt < 4; ++nt)
#pragma unroll
        for (int mt = 0; mt < 2; ++mt) {
          acc[mt][nt] = MFMA(ah[cur][mt], bh[cur][nt], acc[mt][nt], 0, 0, 0);
          acc[mt][nt] = MFMA(al[cur][mt], bh[cur][nt], acc[mt][nt], 0, 0, 0);
          acc[mt][nt] = MFMA(ah[cur][mt], bl[cur][nt], acc[mt][nt], 0, 0, 0);
        }
    }
  }

  // epilogue: bias+relu -> H1 hi bf16, stage + coalesced store
#pragma unroll
  for (int mt = 0; mt < 2; ++mt) {
    const int h0 = hbase + mt * 16 + q * 4;
    const float* bp = &b1[h0];
#pragma unroll
    for (int nt = 0; nt < 4; ++nt) {
      const int e = nt * 16 + lr;
      bf16x4 hh;
#pragma unroll
      for (int r = 0; r < 4; ++r)
        hh[r] = (bf16)fmaxf(acc[mt][nt][r] + bp[r], 0.f);
      *(bf16x4*)&R[e * 136 + h0] = hh;
    }
  }
  bar_lds();
#pragma unroll
  for (int it = 0; it < 4; ++it) {
    const int idx = it * 256 + tid;
    const int row = idx >> 4;
    const int f8 = (idx & 15) * 8;
    const int n = n0 + row;
    if (n < N)
      *(bf16x8*)&P[(size_t)n * 128 + f8] = *(const bf16x8*)&R[row * 136 + f8];
  }
}

// ---------------- global-MLP body (shared by fused + standalone) ----------
__device__ __forceinline__ void gmlp_dev(
    int b, int t, const float* __restrict__ uin, float* __restrict__ gx,
    const int* __restrict__ gcnt,
    const float* __restrict__ gw1, const float* __restrict__ gb1,
    const float* __restrict__ gw2, const float* __restrict__ gb2,
    float* __restrict__ uout,
    const float* __restrict__ w1n, const float* __restrict__ b1n,
    const float* __restrict__ pbn, float* __restrict__ UW, int has_next) {
  __shared__ float g[256];
  __shared__ float g1[128];
  const bool act = t < 128;
  const int c = gcnt[b];
  const float inv = 1.f / (float)(c > 1 ? c : 1);
  if (act) {
    g[t] = uin[b * 128 + t];
    g[128 + t] = gx[b * 128 + t] * inv;
    gx[b * 128 + t] = 0.f;
  }
  __syncthreads();
  float acc = 0.f;
  if (act) {
    acc = gb1[t];
#pragma unroll 8
    for (int k = 0; k < 256; ++k) acc = fmaf(g[k], gw1[k * 128 + t], acc);
    g1[t] = fmaxf(acc, 0.f);
  }
  __syncthreads();
  float acc2 = 0.f;
  if (act) {
    acc2 = gb2[t];
#pragma unroll 8
    for (int k = 0; k < 128; ++k) acc2 = fmaf(g1[k], gw2[k * 128 + t], acc2);
    uout[b * 128 + t] = acc2;
  }
  if (has_next) {
    __syncthreads();
    if (act) g[t] = acc2;
    __syncthreads();
    if (act) {
      float s = b1n[t];
#pragma unroll 8
      for (int k = 0; k < 128; ++k)
        s = fmaf(g[k], w1n[(size_t)(256 + k) * 128 + t], s);
#pragma unroll 8
      for (int k = 0; k < 128; ++k)
        s = fmaf(pbn[k], w1n[(size_t)(128 + k) * 128 + t], s);
      UW[b * 128 + t] = s;
    }
  }
}

// ---------------- CSR mean-aggregate (wide gather) + fused gmlp tail -----
// Gather: 2 edges per wave-instruction (32 lanes x 8 B cover one 256 B H1
// row; lane parity p = lane>>5 picks the edge). Halves VMEM instruction
// count and doubles per-wave edge ILP vs the 4 B/lane version.
// Blocks [nAgg, nAgg+B) run the previous layer's global MLP concurrently.
__global__ __launch_bounds__(256, 8)
void agg_csr(const bf16* __restrict__ P, const int* __restrict__ colptr,
             const int* __restrict__ esrow,
             bf16* __restrict__ aggh, bf16* __restrict__ aggl, int N, int E,
             int nAgg,
             const float* __restrict__ uin, float* __restrict__ gx,
             const int* __restrict__ gcnt,
             const float* __restrict__ gw1, const float* __restrict__ gb1,
             const float* __restrict__ gw2, const float* __restrict__ gb2,
             float* __restrict__ uout,
             const float* __restrict__ w1n, const float* __restrict__ b1n,
             const float* __restrict__ pbn, float* __restrict__ UW) {
  if ((int)blockIdx.x >= nAgg) {
    gmlp_dev(blockIdx.x - nAgg, threadIdx.x, uin, gx, gcnt, gw1, gb1, gw2, gb2,
             uout, w1n, b1n, pbn, UW, 1);
    return;
  }
  const int lane = threadIdx.x & 63;
  const int c = blockIdx.x * 4 + (threadIdx.x >> 6);
  if (c >= N) return;
  const int p = lane >> 5;        // edge parity handled by this half-wave
  const int fl = lane & 31;       // feature quad: elements fl*4 .. fl*4+3
  const int beg = colptr[c];
  const int end = (c == N - 1) ? E : colptr[c + 1];
  float s[4] = {0.f, 0.f, 0.f, 0.f};
  int e = beg;
  for (; e + 8 <= end; e += 8) {
    int r[4];
#pragma unroll
    for (int j = 0; j < 4; ++j) r[j] = esrow[e + 2 * j + p];
    uint2 v[4];
#pragma unroll
    for (int j = 0; j < 4; ++j)
      v[j] = *(const uint2*)&P[(size_t)r[j] * 128 + fl * 4];
#pragma unroll
    for (int j = 0; j < 4; ++j) {
      s[0] += bfhi_f(v[j].x);
      s[1] += bflo_f(v[j].x);
      s[2] += bfhi_f(v[j].y);
      s[3] += bflo_f(v[j].y);
    }
  }
  const int rem = end - e;
  if (rem > 0) {
    int r[4];
    bool m[4];
#pragma unroll
    for (int j = 0; j < 4; ++j) {
      const int idx = 2 * j + p;
      m[j] = idx < rem;
      r[j] = esrow[e + (m[j] ? idx : 0)];
    }
    uint2 v[4];
#pragma unroll
    for (int j = 0; j < 4; ++j)
      v[j] = *(const uint2*)&P[(size_t)r[j] * 128 + fl * 4];
#pragma unroll
    for (int j = 0; j < 4; ++j) {
      if (m[j]) {
        s[0] += bfhi_f(v[j].x);
        s[1] += bflo_f(v[j].x);
        s[2] += bfhi_f(v[j].y);
        s[3] += bflo_f(v[j].y);
      }
    }
  }
  // cross-parity reduce: lane L += lane L^32
#pragma unroll
  for (int k = 0; k < 4; ++k) s[k] += __shfl_xor(s[k], 32);
  const int cc = end - beg;
  const float inv = 1.f / (float)(cc > 1 ? cc : 1);
  if (p == 0) {
    bf16x4 h4, l4;
#pragma unroll
    for (int k = 0; k < 4; ++k) {
      const float v = s[k] * inv;
      h4[k] = (bf16)v;
      l4[k] = (bf16)(v - (float)h4[k]);
    }
    *(bf16x4*)&aggh[(size_t)c * 128 + fl * 4] = h4;
    *(bf16x4*)&aggl[(size_t)c * 128 + fl * 4] = l4;
  }
}

// ---------------- fused node MLP + gsum + next-layer H1 (R5 best) --------
__global__ __launch_bounds__(256, 3)
void node_p(bf16* xh, bf16* xl,
            const bf16* __restrict__ aggh, const bf16* __restrict__ aggl,
            const float* __restrict__ UW, const int* __restrict__ batch,
            const bf16* __restrict__ w1t, const bf16* __restrict__ w2t,
            const float* __restrict__ b2,
            const bf16* __restrict__ w1te, const float* __restrict__ b1e,
            bf16* __restrict__ Pout, float* __restrict__ gx,
            float* __restrict__ xout, int write_x, int has_next, int N) {
  __shared__ __align__(16) bf16 R[2 * 64 * 136];   // 34.8 KB, time-shared
  __shared__ int sbatch[64];

  const int tid = threadIdx.x;
  const int n0 = blockIdx.x * 64;
  const int wave = tid >> 6, lane = tid & 63, q = lane >> 4, lr = lane & 15;
  const int hbase = wave * 32;

  if (tid < 64) {
    int n = n0 + tid;
    sbatch[tid] = batch[(n > N - 1) ? (N - 1) : n];
  }

  int nn[4], ub[4];
#pragma unroll
  for (int nt = 0; nt < 4; ++nt) {
    int n = n0 + nt * 16 + lr;
    if (n > N - 1) n = N - 1;
    nn[nt] = n;
    ub[nt] = batch[n];
  }

  floatx4 acc[2][4];
#pragma unroll
  for (int mt = 0; mt < 2; ++mt)
#pragma unroll
    for (int nt = 0; nt < 4; ++nt)
      acc[mt][nt] = *(const floatx4*)&UW[(size_t)ub[nt] * 128 + hbase + mt * 16 + q * 4];

  // GEMM1: K=256 (x hi/lo | aggH1 hi/lo vs fused weight), A and B dbuf
  {
    bf16x8 bh[2][4], bl[2][4], ah[2][2], al[2][2];
    auto loadB = [&](int kc, int buf) {
#pragma unroll
      for (int nt = 0; nt < 4; ++nt) {
        if (kc < 4) {
          const size_t off = (size_t)nn[nt] * 128 + kc * 32 + q * 8;
          bh[buf][nt] = *(const bf16x8*)(xh + off);
          bl[buf][nt] = *(const bf16x8*)(xl + off);
        } else {
          const size_t off = (size_t)nn[nt] * 128 + (kc - 4) * 32 + q * 8;
          bh[buf][nt] = *(const bf16x8*)(aggh + off);
          bl[buf][nt] = *(const bf16x8*)(aggl + off);
        }
      }
    };
    auto loadA = [&](int kc, int buf) {
#pragma unroll
      for (int mt = 0; mt < 2; ++mt) {
        const bf16* wp = w1t + (size_t)(hbase + mt * 16 + lr) * 256 + kc * 32 + q * 8;
        ah[buf][mt] = *(const bf16x8*)wp;
        al[buf][mt] = *(const bf16x8*)(wp + 32768);
      }
    };
    loadA(0, 0);
    loadB(0, 0);
#pragma unroll
    for (int kc = 0; kc < 8; ++kc) {
      const int cur = kc & 1, nxt = cur ^ 1;
      if (kc < 7) {
        loadA(kc + 1, nxt);
        loadB(kc + 1, nxt);
      }
#pragma unroll
      for (int nt = 0; nt < 4; ++nt)
#pragma unroll
        for (int mt = 0; mt < 2; ++mt) {
          acc[mt][nt] = MFMA(ah[cur][mt], bh[cur][nt], acc[mt][nt], 0, 0, 0);
          acc[mt][nt] = MFMA(al[cur][mt], bh[cur][nt], acc[mt][nt], 0, 0, 0);
          acc[mt][nt] = MFMA(ah[cur][mt], bl[cur][nt], acc[mt][nt], 0, 0, 0);
        }
    }
  }

  // prefetch GEMM2 ks=0 A-frags (fly across epilogue + barrier)
  bf16x8 a2h[2][2], a2l[2][2];
#pragma unroll
  for (int mt = 0; mt < 2; ++mt) {
    const bf16* wp = w2t + (size_t)(hbase + mt * 16 + lr) * 128 + q * 8;
    a2h[0][mt] = *(const bf16x8*)wp;
    a2l[0][mt] = *(const bf16x8*)(wp + 16384);
  }

  // epilogue 1: relu (b1 folded in UW) -> H1 hi/lo
  const floatx4 zz = {0.f, 0.f, 0.f, 0.f};
#pragma unroll
  for (int mt = 0; mt < 2; ++mt) {
    const int h0 = hbase + mt * 16 + q * 4;
#pragma unroll
    for (int nt = 0; nt < 4; ++nt) {
      const int e = nt * 16 + lr;
      bf16x4 hh, ll;
#pragma unroll
      for (int r = 0; r < 4; ++r) {
        const float v = fmaxf(acc[mt][nt][r], 0.f);
        hh[r] = (bf16)v;
        ll[r] = (bf16)(v - (float)hh[r]);
      }
      *(bf16x4*)&R[e * 136 + h0] = hh;
      *(bf16x4*)&R[64 * 136 + e * 136 + h0] = ll;
      acc[mt][nt] = zz;
    }
  }
  bar_lds();

  // GEMM2: A double-buffered from global, B from LDS
#pragma unroll
  for (int ks = 0; ks < 4; ++ks) {
    const int cur = ks & 1, nxt = cur ^ 1;
    if (ks < 3) {
#pragma unroll
      for (int mt = 0; mt < 2; ++mt) {
        const bf16* wp = w2t + (size_t)(hbase + mt * 16 + lr) * 128 + (ks + 1) * 32 + q * 8;
        a2h[nxt][mt] = *(const bf16x8*)wp;
        a2l[nxt][mt] = *(const bf16x8*)(wp + 16384);
      }
    }
    bf16x8 b2h[4], b2l[4];
#pragma unroll
    for (int nt = 0; nt < 4; ++nt) {
      const bf16* hp = &R[(nt * 16 + lr) * 136 + ks * 32 + q * 8];
      b2h[nt] = *(const bf16x8*)hp;
      b2l[nt] = *(const bf16x8*)(hp + 64 * 136);
    }
#pragma unroll
    for (int nt = 0; nt < 4; ++nt)
#pragma unroll
      for (int mt = 0; mt < 2; ++mt) {
        acc[mt][nt] = MFMA(a2h[cur][mt], b2h[nt], acc[mt][nt], 0, 0, 0);
        acc[mt][nt] = MFMA(a2l[cur][mt], b2h[nt], acc[mt][nt], 0, 0, 0);
        acc[mt][nt] = MFMA(a2h[cur][mt], b2l[nt], acc[mt][nt], 0, 0, 0);
      }
  }
  bar_lds();   // H1 reads done; Xt fp32 [64][132] overlays R

  // prefetch H1p-GEMM kc=0 A-frags (fly across epilogue2 + stores + gsum)
  bf16x8 pah[2][2], pal[2][2];
  if (has_next) {
#pragma unroll
    for (int mt = 0; mt < 2; ++mt) {
      const bf16* wp = w1te + (size_t)(hbase + mt * 16 + lr) * 128 + q * 8;
      pah[0][mt] = *(const bf16x8*)wp;
      pal[0][mt] = *(const bf16x8*)(wp + 16384);
    }
  }

  // epilogue 2: +b2 -> Xt
  float* Xt = (float*)&R[0];
#pragma unroll
  for (int mt = 0; mt < 2; ++mt) {
    const int f0 = hbase + mt * 16 + q * 4;
    const float* bp = &b2[f0];
#pragma unroll
    for (int nt = 0; nt < 4; ++nt) {
      const int e = nt * 16 + lr;
      const int n = n0 + e;
      float4 o;
      o.x = (n < N) ? acc[mt][nt][0] + bp[0] : 0.f;
      o.y = (n < N) ? acc[mt][nt][1] + bp[1] : 0.f;
      o.z = (n < N) ? acc[mt][nt][2] + bp[2] : 0.f;
      o.w = (n < N) ? acc[mt][nt][3] + bp[3] : 0.f;
      *(float4*)&Xt[e * 132 + f0] = o;
    }
  }
  bar_lds();

  // coalesced xh/xl stores (next layer), optional xout
  if (has_next) {
#pragma unroll
    for (int it = 0; it < 4; ++it) {
      const int idx = it * 256 + tid;
      const int row = idx >> 4;
      const int f8 = (idx & 15) * 8;
      const int n = n0 + row;
      if (n < N) {
        bf16x8 hh, ll;
#pragma unroll
        for (int j = 0; j < 8; ++j) {
          const float v = Xt[row * 132 + f8 + j];
          hh[j] = (bf16)v;
          ll[j] = (bf16)(v - (float)hh[j]);
        }
        *(bf16x8*)&xh[(size_t)n * 128 + f8] = hh;
        *(bf16x8*)&xl[(size_t)n * 128 + f8] = ll;
      }
    }
  }
  if (write_x) {
#pragma unroll
    for (int it = 0; it < 8; ++it) {
      const int idx = it * 256 + tid;
      const int row = idx >> 5;
      const int f4 = (idx & 31) * 4;
      const int n = n0 + row;
      if (n < N)
        *(float4*)&xout[(size_t)n * 128 + f4] = *(const float4*)&Xt[row * 132 + f4];
    }
  }

  // fused gsum: segmented reduce over 64 sorted-batch nodes
  {
    const int f = tid & 127;
    const int es = (tid >> 7) * 32;
    int cur = sbatch[es];
    float s = 0.f;
    for (int e = es; e < es + 32; ++e) {
      const int b = sbatch[e];
      const float v = Xt[e * 132 + f];
      if (b != cur) {
        atomicAdd(&gx[(size_t)cur * 128 + f], s);
        s = 0.f;
        cur = b;
      }
      s += v;
    }
    atomicAdd(&gx[(size_t)cur * 128 + f], s);
  }

  if (!has_next) return;

  // H1p phase: Pout = relu(Xnew@W1e + b1e) (hi bf16) — W2e fused downstream
  floatx4 pacc[2][4];
#pragma unroll
  for (int mt = 0; mt < 2; ++mt)
#pragma unroll
    for (int nt = 0; nt < 4; ++nt) pacc[mt][nt] = zz;

#pragma unroll
  for (int kc = 0; kc < 4; ++kc) {
    const int cur = kc & 1, nxt = cur ^ 1;
    if (kc < 3) {
#pragma unroll
      for (int mt = 0; mt < 2; ++mt) {
        const bf16* wp = w1te + (size_t)(hbase + mt * 16 + lr) * 128 + (kc + 1) * 32 + q * 8;
        pah[nxt][mt] = *(const bf16x8*)wp;
        pal[nxt][mt] = *(const bf16x8*)(wp + 16384);
      }
    }
    bf16x8 bh[4], bl[4];
#pragma unroll
    for (int nt = 0; nt < 4; ++nt) {
      const float* xp = &Xt[(nt * 16 + lr) * 132 + kc * 32 + q * 8];
#pragma unroll
      for (int r = 0; r < 8; ++r) {
        const float v = xp[r];
        bh[nt][r] = (bf16)v;
        bl[nt][r] = (bf16)(v - (float)bh[nt][r]);
      }
    }
#pragma unroll
    for (int nt = 0; nt < 4; ++nt)
#pragma unroll
      for (int mt = 0; mt < 2; ++mt) {
        pacc[mt][nt] = MFMA(pah[cur][mt], bh[nt], pacc[mt][nt], 0, 0, 0);
        pacc[mt][nt] = MFMA(pal[cur][mt], bh[nt], pacc[mt][nt], 0, 0, 0);
        pacc[mt][nt] = MFMA(pah[cur][mt], bl[nt], pacc[mt][nt], 0, 0, 0);
      }
  }
  bar_lds();   // Xt reads (incl. gsum) done; H1p hi staging overlays R

  // epilogue: +b1e, relu -> hi bf16 stage, coalesced store
#pragma unroll
  for (int mt = 0; mt < 2; ++mt) {
    const int h0 = hbase + mt * 16 + q * 4;
    const float* bp = &b1e[h0];
#pragma unroll
    for (int nt = 0; nt < 4; ++nt) {
      const int e = nt * 16 + lr;
      bf16x4 hh;
#pragma unroll
      for (int r = 0; r < 4; ++r)
        hh[r] = (bf16)fmaxf(pacc[mt][nt][r] + bp[r], 0.f);
      *(bf16x4*)&R[e * 136 + h0] = hh;
    }
  }
  bar_lds();
#pragma unroll
  for (int it = 0; it < 4; ++it) {
    const int idx = it * 256 + tid;
    const int row = idx >> 4;
    const int f8 = (idx & 15) * 8;
    const int n = n0 + row;
    if (n < N)
      *(bf16x8*)&Pout[(size_t)n * 128 + f8] = *(const bf16x8*)&R[row * 136 + f8];
  }
}

// ---------------- UW = u @ W1c + b1 + b2e @ W1a (layer 0) ----------------
__global__ void uw_kernel(const float* __restrict__ u, const float* __restrict__ w1,
                          const float* __restrict__ b1, const float* __restrict__ pb,
                          float* __restrict__ UW) {
  const int b = blockIdx.x, h = threadIdx.x;
  float s = b1[h];
#pragma unroll 8
  for (int k = 0; k < 128; ++k)
    s = fmaf(u[b * 128 + k], w1[(size_t)(256 + k) * 128 + h], s);
#pragma unroll 8
  for (int k = 0; k < 128; ++k)
    s = fmaf(pb[k], w1[(size_t)(128 + k) * 128 + h], s);
  UW[b * 128 + h] = s;
}

// ---------------- standalone global MLP (last layer only) ----------------
__global__ __launch_bounds__(128)
void gmlp_kernel(const float* __restrict__ uin, float* __restrict__ gx,
                 const int* __restrict__ gcnt,
                 const float* __restrict__ gw1, const float* __restrict__ gb1,
                 const float* __restrict__ gw2, const float* __restrict__ gb2,
                 float* __restrict__ uout,
                 const float* __restrict__ w1n, const float* __restrict__ b1n,
                 const float* __restrict__ pbn, float* __restrict__ UW,
                 int has_next) {
  gmlp_dev(blockIdx.x, threadIdx.x, uin, gx, gcnt, gw1, gb1, gw2, gb2,
           uout, w1n, b1n, pbn, UW, has_next);
}

// ---------------- host ----------------
extern "C" void kernel_launch(void* const* d_in, const int* in_sizes, int n_in,
                              void* d_out, int out_size, void* d_ws, size_t ws_size,
                              hipStream_t stream) {
  constexpr int N = 50000, E = 600000, B = 64, F = 128, L = 4;

  const float* x0    = (const float*)d_in[0];
  const int*   ei    = (const int*)  d_in[1];
  const float* u0    = (const float*)d_in[2];
  const int*   batch = (const int*)  d_in[3];
  const float* n1w1  = (const float*)d_in[4];
  const float* n1b1  = (const float*)d_in[5];
  const float* n1w2  = (const float*)d_in[6];
  const float* n1b2  = (const float*)d_in[7];
  const float* n2w1  = (const float*)d_in[8];
  const float* n2b1  = (const float*)d_in[9];
  const float* n2w2  = (const float*)d_in[10];
  const float* n2b2  = (const float*)d_in[11];
  const float* gw1   = (const float*)d_in[12];
  const float* gb1   = (const float*)d_in[13];
  const float* gw2   = (const float*)d_in[14];
  const float* gb2   = (const float*)d_in[15];
  float* out = (float*)d_out;

  char* p = (char*)d_ws;
  auto carve = [&](size_t bytes) -> void* {
    void* q = (void*)p;
    p += (bytes + 255) & ~(size_t)255;
    return q;
  };
  float* ubuf  = (float*)carve((size_t)B * F * 4);
  float* gx    = (float*)carve((size_t)B * F * 4);
  float* UW    = (float*)carve((size_t)B * F * 4);
  int*   cnt   = (int*)carve((size_t)N * 4);
  int*   colptr= (int*)carve((size_t)(N + 1) * 4);
  int*   rctr  = (int*)carve((size_t)N * 4);
  int*   gcnt  = (int*)carve((size_t)B * 4);
  int*   btot  = (int*)carve(32 * 4);
  int*   esrow = (int*)carve((size_t)E * 4);
  bf16*  xhi   = (bf16*)carve((size_t)N * F * 2);
  bf16*  xlo   = (bf16*)carve((size_t)N * F * 2);
  bf16*  P_a   = (bf16*)carve((size_t)N * F * 2);
  bf16*  P_b   = (bf16*)carve((size_t)N * F * 2);
  bf16*  aggh  = (bf16*)carve((size_t)N * F * 2);
  bf16*  aggl  = (bf16*)carve((size_t)N * F * 2);
  bf16*  w1t_e = (bf16*)carve((size_t)L * 2 * 128 * 128 * 2);
  bf16*  w1t_n = (bf16*)carve((size_t)L * 2 * 256 * 128 * 2);
  bf16*  w2t_n = (bf16*)carve((size_t)L * 2 * 128 * 128 * 2);
  float* wtmp  = (float*)carve((size_t)L * 256 * 128 * 4);

  constexpr int SCAN_BLOCKS = (N + 2047) / 2048;

  hipMemsetAsync(cnt, 0, (size_t)N * 4, stream);
  hipMemsetAsync(gx, 0, (size_t)B * F * 4, stream);   // re-zeroed by gmlp
  hist_kernel<<<(E + 255) / 256, 256, 0, stream>>>(ei, cnt, E);
  gcnt_kernel<<<1, 64, 0, stream>>>(batch, gcnt, N, B);
  scan1_kernel<<<SCAN_BLOCKS, 256, 0, stream>>>(cnt, colptr, rctr, btot, N);
  scan2_kernel<<<SCAN_BLOCKS, 256, 0, stream>>>(colptr, rctr, btot, N);
  place_kernel<<<(E + 255) / 256, 256, 0, stream>>>(ei, rctr, esrow, E);
  wsplit_kernel<<<dim3(64, L), 256, 0, stream>>>(n1w1, w1t_e, 128, 128, 128);
  wfuse_kernel<<<dim3(128, L), 128, 0, stream>>>(n2w1, n1w2, wtmp);
  wsplit_kernel<<<dim3(128, L), 256, 0, stream>>>(wtmp, w1t_n, 256, 256, 128);
  wsplit_kernel<<<dim3(64, L), 256, 0, stream>>>(n2w2, w2t_n, 128, 128, 128);
  xsplit_kernel<<<(N * F / 4 + 255) / 256, 256, 0, stream>>>(x0, xhi, xlo, N * F / 4);
  uw_kernel<<<B, 128, 0, stream>>>(u0, n2w1, n2b1, n1b2, UW);

  const int NB = (N + 63) / 64;
  const int NAGG = (N + 3) / 4;
  pnode_mfma<<<NB, 256, 0, stream>>>(xhi, xlo, w1t_e, n1b1, P_a, N);

  // layer-0 aggregate (no gmlp blocks: grid == NAGG)
  agg_csr<<<NAGG, 256, 0, stream>>>(P_a, colptr, esrow, aggh, aggl, N, E, NAGG,
      u0, gx, gcnt, gw1, gb1, gw2, gb2, ubuf, n2w1, n2b1, n1b2, UW);

  for (int l = 0; l < L; ++l) {
    const int    wx   = (l == L - 1) ? 1 : 0;
    const int    hn   = (l < L - 1) ? 1 : 0;
    bf16*        Pout = (l & 1) ? P_a : P_b;
    const int    le   = hn ? (l + 1) : l;

    node_p<<<NB, 256, 0, stream>>>(
        xhi, xlo, aggh, aggl, UW, batch,
        w1t_n + (size_t)l * 65536, w2t_n + (size_t)l * 32768,
        n2b2 + l * 128,
        w1t_e + (size_t)le * 32768, n1b1 + le * 128,
        Pout, gx, out, wx, hn, N);

    if (l < L - 1) {
      // aggregate for layer l+1, with this layer's gmlp fused in as B blocks
      agg_csr<<<NAGG + B, 256, 0, stream>>>(
          Pout, colptr, esrow, aggh, aggl, N, E, NAGG,
          (l ? ubuf : u0), gx, gcnt,
          gw1 + (size_t)l * 256 * 128, gb1 + l * 128,
          gw2 + (size_t)l * 128 * 128, gb2 + l * 128,
          ubuf,
          n2w1 + (size_t)(l + 1) * 384 * 128, n2b1 + (l + 1) * 128,
          n1b2 + (l + 1) * 128, UW);
    } else {
      gmlp_kernel<<<B, 128, 0, stream>>>(
          ubuf, gx, gcnt,
          gw1 + (size_t)l * 256 * 128, gb1 + l * 128,
          gw2 + (size_t)l * 128 * 128, gb2 + l * 128,
          out + (size_t)N * F,
          n2w1, n2b1, n1b2, UW, 0);
    }
  }
}

// Round 9
// 674.917 us; speedup vs baseline: 1.1755x; 1.0394x over previous
//
#include <hip/hip_runtime.h>

typedef __bf16 bf16;
typedef bf16 bf16x8 __attribute__((ext_vector_type(8)));
typedef bf16 bf16x4 __attribute__((ext_vector_type(4)));
typedef bf16 bf16x2 __attribute__((ext_vector_type(2)));
typedef float floatx4 __attribute__((ext_vector_type(4)));

#define MFMA __builtin_amdgcn_mfma_f32_16x16x32_bf16

__device__ __forceinline__ float bfhi_f(unsigned u) {
  const unsigned x = u << 16;
  return __builtin_bit_cast(float, x);
}
__device__ __forceinline__ float bflo_f(unsigned u) {
  const unsigned x = u & 0xffff0000u;
  return __builtin_bit_cast(float, x);
}

// LDS-only barrier: waits for this wave's LDS ops (lgkmcnt) then syncs the
// block, WITHOUT the vmcnt(0) drain __syncthreads() emits.
__device__ __forceinline__ void bar_lds() {
  asm volatile("s_waitcnt lgkmcnt(0)" ::: "memory");
  __builtin_amdgcn_s_barrier();
}

// ---------------- setup kernels ----------------

__global__ void hist_kernel(const int* __restrict__ ei, int* __restrict__ cnt, int E) {
  int e = blockIdx.x * blockDim.x + threadIdx.x;
  if (e < E) atomicAdd(&cnt[ei[E + e]], 1);
}

__global__ void gcnt_kernel(const int* __restrict__ batch, int* __restrict__ gcnt,
                            int N, int B) {
  const int b = threadIdx.x;
  if (b >= B) return;
  auto lb = [&](int v) {
    int lo = 0, hi = N;
    while (lo < hi) {
      const int mid = (lo + hi) >> 1;
      if (batch[mid] < v) lo = mid + 1; else hi = mid;
    }
    return lo;
  };
  gcnt[b] = lb(b + 1) - lb(b);
}

__global__ void scan1_kernel(const int* __restrict__ cnt, int* __restrict__ colptr,
                             int* __restrict__ rctr, int* __restrict__ btot, int n) {
  __shared__ int sd[256];
  const int tid = threadIdx.x;
  const int i0 = blockIdx.x * 2048 + tid * 8;
  int v[8];
  int tot = 0;
#pragma unroll
  for (int j = 0; j < 8; ++j) {
    const int i = i0 + j;
    v[j] = (i < n) ? cnt[i] : 0;
    tot += v[j];
  }
  sd[tid] = tot;
  __syncthreads();
  for (int off = 1; off < 256; off <<= 1) {
    const int t = (tid >= off) ? sd[tid - off] : 0;
    __syncthreads();
    sd[tid] += t;
    __syncthreads();
  }
  int excl = sd[tid] - tot;
#pragma unroll
  for (int j = 0; j < 8; ++j) {
    const int i = i0 + j;
    if (i < n) { colptr[i] = excl; rctr[i] = excl; }
    excl += v[j];
  }
  if (tid == 255) btot[blockIdx.x] = sd[255];
}

__global__ void scan2_kernel(int* __restrict__ colptr, int* __restrict__ rctr,
                             const int* __restrict__ btot, int n) {
  __shared__ int off_s;
  const int tid = threadIdx.x;
  if (blockIdx.x == 0) return;
  if (tid == 0) {
    int o = 0;
    for (int j = 0; j < (int)blockIdx.x; ++j) o += btot[j];
    off_s = o;
  }
  __syncthreads();
  const int off = off_s;
  const int i0 = blockIdx.x * 2048 + tid * 8;
#pragma unroll
  for (int j = 0; j < 8; ++j) {
    const int i = i0 + j;
    if (i < n) { colptr[i] += off; rctr[i] += off; }
  }
}

__global__ void place_kernel(const int* __restrict__ ei, int* __restrict__ rctr,
                             int* __restrict__ esrow, int E) {
  int e = blockIdx.x * blockDim.x + threadIdx.x;
  if (e >= E) return;
  const int r = ei[e];
  const int c = ei[E + e];
  const int p = atomicAdd(&rctr[c], 1);
  esrow[p] = r;
}

// transpose+split: src [L][Ksrc][H] fp32 (first K rows) -> dst [L][2][H][K] bf16
__global__ void wsplit_kernel(const float* __restrict__ src, bf16* __restrict__ dst,
                              int Ksrc, int K, int HH) {
  const int l = blockIdx.y;
  const int gid = blockIdx.x * blockDim.x + threadIdx.x;
  if (gid >= K * HH) return;
  const int h = gid / K, k = gid - h * K;
  const float v = src[(size_t)l * Ksrc * HH + (size_t)k * HH + h];
  const bf16 hi = (bf16)v;
  const bf16 lo = (bf16)(v - (float)hi);
  bf16* d = dst + (size_t)l * 2 * K * HH;
  d[(size_t)h * K + k] = hi;
  d[(size_t)K * HH + (size_t)h * K + k] = lo;
}

// Build fused node-GEMM1 weight G[l] (256x128 fp32):
//   rows   0..127 : x-part      = n2w1[l][0:128]
//   rows 128..255 : agg-part    = n1w2[l] @ n2w1[l][128:256]
__global__ void wfuse_kernel(const float* __restrict__ n2w1,
                             const float* __restrict__ n1w2,
                             float* __restrict__ G) {
  const int l = blockIdx.y, k = blockIdx.x, h = threadIdx.x;
  const float* w = n2w1 + (size_t)l * 384 * 128;
  float* g = G + (size_t)l * 256 * 128;
  g[(size_t)k * 128 + h] = w[(size_t)k * 128 + h];
  const float* a = n1w2 + (size_t)l * 128 * 128 + (size_t)k * 128;
  float s = 0.f;
#pragma unroll 8
  for (int j = 0; j < 128; ++j)
    s = fmaf(a[j], w[(size_t)(128 + j) * 128 + h], s);
  g[(size_t)(128 + k) * 128 + h] = s;
}

__global__ void xsplit_kernel(const float* __restrict__ x, bf16* __restrict__ xhi,
                              bf16* __restrict__ xlo, int n4) {
  const int i = blockIdx.x * 256 + threadIdx.x;
  if (i >= n4) return;
  const float4 v = ((const float4*)x)[i];
  bf16x4 h, l;
  const float vv[4] = {v.x, v.y, v.z, v.w};
#pragma unroll
  for (int r = 0; r < 4; ++r) {
    h[r] = (bf16)vv[r];
    l[r] = (bf16)(vv[r] - (float)h[r]);
  }
  *(bf16x4*)&xhi[(size_t)i * 4] = h;
  *(bf16x4*)&xlo[(size_t)i * 4] = l;
}

// ---------------- layer-0 edge MLP: H1 = relu(x@W1e+b1e) only -------------
__global__ __launch_bounds__(256, 3)
void pnode_mfma(const bf16* __restrict__ xh, const bf16* __restrict__ xl,
                const bf16* __restrict__ w1t, const float* __restrict__ b1,
                bf16* __restrict__ P, int N) {
  __shared__ __align__(16) bf16 R[64 * 136];   // 17.4 KB hi-only staging

  const int tid = threadIdx.x;
  const int n0 = blockIdx.x * 64;
  const int wave = tid >> 6, lane = tid & 63, q = lane >> 4, lr = lane & 15;
  const int hbase = wave * 32;

  int nn[4];
#pragma unroll
  for (int nt = 0; nt < 4; ++nt) {
    int n = n0 + nt * 16 + lr;
    nn[nt] = (n > N - 1) ? (N - 1) : n;
  }

  const floatx4 zz = {0.f, 0.f, 0.f, 0.f};
  floatx4 acc[2][4];
#pragma unroll
  for (int mt = 0; mt < 2; ++mt)
#pragma unroll
    for (int nt = 0; nt < 4; ++nt) acc[mt][nt] = zz;

  // GEMM1: K=128, A and B double-buffered
  {
    bf16x8 bh[2][4], bl[2][4], ah[2][2], al[2][2];
    auto loadA = [&](int kc, int buf) {
#pragma unroll
      for (int mt = 0; mt < 2; ++mt) {
        const bf16* wp = w1t + (size_t)(hbase + mt * 16 + lr) * 128 + kc * 32 + q * 8;
        ah[buf][mt] = *(const bf16x8*)wp;
        al[buf][mt] = *(const bf16x8*)(wp + 16384);
      }
    };
    auto loadB = [&](int kc, int buf) {
#pragma unroll
      for (int nt = 0; nt < 4; ++nt) {
        const size_t off = (size_t)nn[nt] * 128 + kc * 32 + q * 8;
        bh[buf][nt] = *(const bf16x8*)(xh + off);
        bl[buf][nt] = *(const bf16x8*)(xl + off);
      }
    };
    loadA(0, 0);
    loadB(0, 0);
#pragma unroll
    for (int kc = 0; kc < 4; ++kc) {
      const int cur = kc & 1, nxt = cur ^ 1;
      if (kc < 3) {
        loadA(kc + 1, nxt);
        loadB(kc + 1, nxt);
      }
#pragma unroll
      for (int nt = 0; nt < 4; ++nt)
#pragma unroll
        for (int mt = 0; mt < 2; ++mt) {
          acc[mt][nt] = MFMA(ah[cur][mt], bh[cur][nt], acc[mt][nt], 0, 0, 0);
          acc[mt][nt] = MFMA(al[cur][mt], bh[cur][nt], acc[mt][nt], 0, 0, 0);
          acc[mt][nt] = MFMA(ah[cur][mt], bl[cur][nt], acc[mt][nt], 0, 0, 0);
        }
    }
  }

  // epilogue: bias+relu -> H1 hi bf16, stage + coalesced store
#pragma unroll
  for (int mt = 0; mt < 2; ++mt) {
    const int h0 = hbase + mt * 16 + q * 4;
    const float* bp = &b1[h0];
#pragma unroll
    for (int nt = 0; nt < 4; ++nt) {
      const int e = nt * 16 + lr;
      bf16x4 hh;
#pragma unroll
      for (int r = 0; r < 4; ++r)
        hh[r] = (bf16)fmaxf(acc[mt][nt][r] + bp[r], 0.f);
      *(bf16x4*)&R[e * 136 + h0] = hh;
    }
  }
  bar_lds();
#pragma unroll
  for (int it = 0; it < 4; ++it) {
    const int idx = it * 256 + tid;
    const int row = idx >> 4;
    const int f8 = (idx & 15) * 8;
    const int n = n0 + row;
    if (n < N)
      *(bf16x8*)&P[(size_t)n * 128 + f8] = *(const bf16x8*)&R[row * 136 + f8];
  }
}

// ---------------- global-MLP body (shared by fused + standalone) ----------
__device__ __forceinline__ void gmlp_dev(
    int b, int t, const float* __restrict__ uin, float* __restrict__ gx,
    const int* __restrict__ gcnt,
    const float* __restrict__ gw1, const float* __restrict__ gb1,
    const float* __restrict__ gw2, const float* __restrict__ gb2,
    float* __restrict__ uout,
    const float* __restrict__ w1n, const float* __restrict__ b1n,
    const float* __restrict__ pbn, float* __restrict__ UW, int has_next) {
  __shared__ float g[256];
  __shared__ float g1[128];
  const bool act = t < 128;
  const int c = gcnt[b];
  const float inv = 1.f / (float)(c > 1 ? c : 1);
  if (act) {
    g[t] = uin[b * 128 + t];
    g[128 + t] = gx[b * 128 + t] * inv;
    gx[b * 128 + t] = 0.f;
  }
  __syncthreads();
  float acc = 0.f;
  if (act) {
    acc = gb1[t];
#pragma unroll 8
    for (int k = 0; k < 256; ++k) acc = fmaf(g[k], gw1[k * 128 + t], acc);
    g1[t] = fmaxf(acc, 0.f);
  }
  __syncthreads();
  float acc2 = 0.f;
  if (act) {
    acc2 = gb2[t];
#pragma unroll 8
    for (int k = 0; k < 128; ++k) acc2 = fmaf(g1[k], gw2[k * 128 + t], acc2);
    uout[b * 128 + t] = acc2;
  }
  if (has_next) {
    __syncthreads();
    if (act) g[t] = acc2;
    __syncthreads();
    if (act) {
      float s = b1n[t];
#pragma unroll 8
      for (int k = 0; k < 128; ++k)
        s = fmaf(g[k], w1n[(size_t)(256 + k) * 128 + t], s);
#pragma unroll 8
      for (int k = 0; k < 128; ++k)
        s = fmaf(pbn[k], w1n[(size_t)(128 + k) * 128 + t], s);
      UW[b * 128 + t] = s;
    }
  }
}

// ---------------- CSR mean-aggregate (2 columns/wave for MLP) ------------
// agg is latency-bound (avg degree 12 => ~1.5 loop iters, only ~8 loads in
// flight per wave). Two independent columns per wave interleave their
// esrow->gather chains: 16 gathers in flight before any waitcnt. Per-column
// guards are wave-uniform (colptr bounds are lane-invariant) => free.
// Blocks [nAgg, nAgg+B) run the previous layer's global MLP concurrently.
__global__ __launch_bounds__(256, 8)
void agg_csr(const bf16* __restrict__ P, const int* __restrict__ colptr,
             const int* __restrict__ esrow,
             bf16* __restrict__ aggh, bf16* __restrict__ aggl, int N, int E,
             int nAgg,
             const float* __restrict__ uin, float* __restrict__ gx,
             const int* __restrict__ gcnt,
             const float* __restrict__ gw1, const float* __restrict__ gb1,
             const float* __restrict__ gw2, const float* __restrict__ gb2,
             float* __restrict__ uout,
             const float* __restrict__ w1n, const float* __restrict__ b1n,
             const float* __restrict__ pbn, float* __restrict__ UW) {
  if ((int)blockIdx.x >= nAgg) {
    gmlp_dev(blockIdx.x - nAgg, threadIdx.x, uin, gx, gcnt, gw1, gb1, gw2, gb2,
             uout, w1n, b1n, pbn, UW, 1);
    return;
  }
  const int wave = threadIdx.x >> 6, lane = threadIdx.x & 63;
  const int c0 = blockIdx.x * 8 + wave * 2;
  if (c0 >= N) return;
  int beg[2], end[2], pos[2];
  float s0[2], s1[2];
#pragma unroll
  for (int j = 0; j < 2; ++j) {
    const int c = c0 + j;
    const bool ok = c < N;
    beg[j] = ok ? colptr[c] : 0;
    end[j] = ok ? ((c == N - 1) ? E : colptr[c + 1]) : 0;
    pos[j] = beg[j];
    s0[j] = 0.f;
    s1[j] = 0.f;
  }
  while ((pos[0] < end[0]) | (pos[1] < end[1])) {
    int r[2][8];
    bool act[2];
#pragma unroll
    for (int j = 0; j < 2; ++j) {
      act[j] = pos[j] < end[j];
      if (act[j]) {
#pragma unroll
        for (int k = 0; k < 8; ++k) {
          const int idx = pos[j] + k;
          r[j][k] = esrow[(idx < end[j]) ? idx : pos[j]];
        }
      }
    }
    unsigned v[2][8];
#pragma unroll
    for (int j = 0; j < 2; ++j)
      if (act[j]) {
#pragma unroll
        for (int k = 0; k < 8; ++k)
          v[j][k] = *(const unsigned*)&P[(size_t)r[j][k] * 128 + lane * 2];
      }
#pragma unroll
    for (int j = 0; j < 2; ++j)
      if (act[j]) {
#pragma unroll
        for (int k = 0; k < 8; ++k) {
          if (pos[j] + k < end[j]) {
            s0[j] += bfhi_f(v[j][k]);
            s1[j] += bflo_f(v[j][k]);
          }
        }
        pos[j] += 8;
      }
  }
#pragma unroll
  for (int j = 0; j < 2; ++j) {
    const int c = c0 + j;
    if (c >= N) continue;
    const int cc = end[j] - beg[j];
    const float inv = 1.f / (float)(cc > 1 ? cc : 1);
    const float v0 = s0[j] * inv;
    const float v1 = s1[j] * inv;
    bf16x2 h, l;
    h[0] = (bf16)v0;  l[0] = (bf16)(v0 - (float)h[0]);
    h[1] = (bf16)v1;  l[1] = (bf16)(v1 - (float)h[1]);
    *(bf16x2*)&aggh[(size_t)c * 128 + lane * 2] = h;
    *(bf16x2*)&aggl[(size_t)c * 128 + lane * 2] = l;
  }
}

// ---------------- fused node MLP + gsum + next-layer H1 (R5 best) --------
__global__ __launch_bounds__(256, 3)
void node_p(bf16* xh, bf16* xl,
            const bf16* __restrict__ aggh, const bf16* __restrict__ aggl,
            const float* __restrict__ UW, const int* __restrict__ batch,
            const bf16* __restrict__ w1t, const bf16* __restrict__ w2t,
            const float* __restrict__ b2,
            const bf16* __restrict__ w1te, const float* __restrict__ b1e,
            bf16* __restrict__ Pout, float* __restrict__ gx,
            float* __restrict__ xout, int write_x, int has_next, int N) {
  __shared__ __align__(16) bf16 R[2 * 64 * 136];   // 34.8 KB, time-shared
  __shared__ int sbatch[64];

  const int tid = threadIdx.x;
  const int n0 = blockIdx.x * 64;
  const int wave = tid >> 6, lane = tid & 63, q = lane >> 4, lr = lane & 15;
  const int hbase = wave * 32;

  if (tid < 64) {
    int n = n0 + tid;
    sbatch[tid] = batch[(n > N - 1) ? (N - 1) : n];
  }

  int nn[4], ub[4];
#pragma unroll
  for (int nt = 0; nt < 4; ++nt) {
    int n = n0 + nt * 16 + lr;
    if (n > N - 1) n = N - 1;
    nn[nt] = n;
    ub[nt] = batch[n];
  }

  floatx4 acc[2][4];
#pragma unroll
  for (int mt = 0; mt < 2; ++mt)
#pragma unroll
    for (int nt = 0; nt < 4; ++nt)
      acc[mt][nt] = *(const floatx4*)&UW[(size_t)ub[nt] * 128 + hbase + mt * 16 + q * 4];

  // GEMM1: K=256 (x hi/lo | aggH1 hi/lo vs fused weight), A and B dbuf
  {
    bf16x8 bh[2][4], bl[2][4], ah[2][2], al[2][2];
    auto loadB = [&](int kc, int buf) {
#pragma unroll
      for (int nt = 0; nt < 4; ++nt) {
        if (kc < 4) {
          const size_t off = (size_t)nn[nt] * 128 + kc * 32 + q * 8;
          bh[buf][nt] = *(const bf16x8*)(xh + off);
          bl[buf][nt] = *(const bf16x8*)(xl + off);
        } else {
          const size_t off = (size_t)nn[nt] * 128 + (kc - 4) * 32 + q * 8;
          bh[buf][nt] = *(const bf16x8*)(aggh + off);
          bl[buf][nt] = *(const bf16x8*)(aggl + off);
        }
      }
    };
    auto loadA = [&](int kc, int buf) {
#pragma unroll
      for (int mt = 0; mt < 2; ++mt) {
        const bf16* wp = w1t + (size_t)(hbase + mt * 16 + lr) * 256 + kc * 32 + q * 8;
        ah[buf][mt] = *(const bf16x8*)wp;
        al[buf][mt] = *(const bf16x8*)(wp + 32768);
      }
    };
    loadA(0, 0);
    loadB(0, 0);
#pragma unroll
    for (int kc = 0; kc < 8; ++kc) {
      const int cur = kc & 1, nxt = cur ^ 1;
      if (kc < 7) {
        loadA(kc + 1, nxt);
        loadB(kc + 1, nxt);
      }
#pragma unroll
      for (int nt = 0; nt < 4; ++nt)
#pragma unroll
        for (int mt = 0; mt < 2; ++mt) {
          acc[mt][nt] = MFMA(ah[cur][mt], bh[cur][nt], acc[mt][nt], 0, 0, 0);
          acc[mt][nt] = MFMA(al[cur][mt], bh[cur][nt], acc[mt][nt], 0, 0, 0);
          acc[mt][nt] = MFMA(ah[cur][mt], bl[cur][nt], acc[mt][nt], 0, 0, 0);
        }
    }
  }

  // prefetch GEMM2 ks=0 A-frags (fly across epilogue + barrier)
  bf16x8 a2h[2][2], a2l[2][2];
#pragma unroll
  for (int mt = 0; mt < 2; ++mt) {
    const bf16* wp = w2t + (size_t)(hbase + mt * 16 + lr) * 128 + q * 8;
    a2h[0][mt] = *(const bf16x8*)wp;
    a2l[0][mt] = *(const bf16x8*)(wp + 16384);
  }

  // epilogue 1: relu (b1 folded in UW) -> H1 hi/lo
  const floatx4 zz = {0.f, 0.f, 0.f, 0.f};
#pragma unroll
  for (int mt = 0; mt < 2; ++mt) {
    const int h0 = hbase + mt * 16 + q * 4;
#pragma unroll
    for (int nt = 0; nt < 4; ++nt) {
      const int e = nt * 16 + lr;
      bf16x4 hh, ll;
#pragma unroll
      for (int r = 0; r < 4; ++r) {
        const float v = fmaxf(acc[mt][nt][r], 0.f);
        hh[r] = (bf16)v;
        ll[r] = (bf16)(v - (float)hh[r]);
      }
      *(bf16x4*)&R[e * 136 + h0] = hh;
      *(bf16x4*)&R[64 * 136 + e * 136 + h0] = ll;
      acc[mt][nt] = zz;
    }
  }
  bar_lds();

  // GEMM2: A double-buffered from global, B from LDS
#pragma unroll
  for (int ks = 0; ks < 4; ++ks) {
    const int cur = ks & 1, nxt = cur ^ 1;
    if (ks < 3) {
#pragma unroll
      for (int mt = 0; mt < 2; ++mt) {
        const bf16* wp = w2t + (size_t)(hbase + mt * 16 + lr) * 128 + (ks + 1) * 32 + q * 8;
        a2h[nxt][mt] = *(const bf16x8*)wp;
        a2l[nxt][mt] = *(const bf16x8*)(wp + 16384);
      }
    }
    bf16x8 b2h[4], b2l[4];
#pragma unroll
    for (int nt = 0; nt < 4; ++nt) {
      const bf16* hp = &R[(nt * 16 + lr) * 136 + ks * 32 + q * 8];
      b2h[nt] = *(const bf16x8*)hp;
      b2l[nt] = *(const bf16x8*)(hp + 64 * 136);
    }
#pragma unroll
    for (int nt = 0; nt < 4; ++nt)
#pragma unroll
      for (int mt = 0; mt < 2; ++mt) {
        acc[mt][nt] = MFMA(a2h[cur][mt], b2h[nt], acc[mt][nt], 0, 0, 0);
        acc[mt][nt] = MFMA(a2l[cur][mt], b2h[nt], acc[mt][nt], 0, 0, 0);
        acc[mt][nt] = MFMA(a2h[cur][mt], b2l[nt], acc[mt][nt], 0, 0, 0);
      }
  }
  bar_lds();   // H1 reads done; Xt fp32 [64][132] overlays R

  // prefetch H1p-GEMM kc=0 A-frags (fly across epilogue2 + stores + gsum)
  bf16x8 pah[2][2], pal[2][2];
  if (has_next) {
#pragma unroll
    for (int mt = 0; mt < 2; ++mt) {
      const bf16* wp = w1te + (size_t)(hbase + mt * 16 + lr) * 128 + q * 8;
      pah[0][mt] = *(const bf16x8*)wp;
      pal[0][mt] = *(const bf16x8*)(wp + 16384);
    }
  }

  // epilogue 2: +b2 -> Xt
  float* Xt = (float*)&R[0];
#pragma unroll
  for (int mt = 0; mt < 2; ++mt) {
    const int f0 = hbase + mt * 16 + q * 4;
    const float* bp = &b2[f0];
#pragma unroll
    for (int nt = 0; nt < 4; ++nt) {
      const int e = nt * 16 + lr;
      const int n = n0 + e;
      float4 o;
      o.x = (n < N) ? acc[mt][nt][0] + bp[0] : 0.f;
      o.y = (n < N) ? acc[mt][nt][1] + bp[1] : 0.f;
      o.z = (n < N) ? acc[mt][nt][2] + bp[2] : 0.f;
      o.w = (n < N) ? acc[mt][nt][3] + bp[3] : 0.f;
      *(float4*)&Xt[e * 132 + f0] = o;
    }
  }
  bar_lds();

  // coalesced xh/xl stores (next layer), optional xout
  if (has_next) {
#pragma unroll
    for (int it = 0; it < 4; ++it) {
      const int idx = it * 256 + tid;
      const int row = idx >> 4;
      const int f8 = (idx & 15) * 8;
      const int n = n0 + row;
      if (n < N) {
        bf16x8 hh, ll;
#pragma unroll
        for (int j = 0; j < 8; ++j) {
          const float v = Xt[row * 132 + f8 + j];
          hh[j] = (bf16)v;
          ll[j] = (bf16)(v - (float)hh[j]);
        }
        *(bf16x8*)&xh[(size_t)n * 128 + f8] = hh;
        *(bf16x8*)&xl[(size_t)n * 128 + f8] = ll;
      }
    }
  }
  if (write_x) {
#pragma unroll
    for (int it = 0; it < 8; ++it) {
      const int idx = it * 256 + tid;
      const int row = idx >> 5;
      const int f4 = (idx & 31) * 4;
      const int n = n0 + row;
      if (n < N)
        *(float4*)&xout[(size_t)n * 128 + f4] = *(const float4*)&Xt[row * 132 + f4];
    }
  }

  // fused gsum: segmented reduce over 64 sorted-batch nodes
  {
    const int f = tid & 127;
    const int es = (tid >> 7) * 32;
    int cur = sbatch[es];
    float s = 0.f;
    for (int e = es; e < es + 32; ++e) {
      const int b = sbatch[e];
      const float v = Xt[e * 132 + f];
      if (b != cur) {
        atomicAdd(&gx[(size_t)cur * 128 + f], s);
        s = 0.f;
        cur = b;
      }
      s += v;
    }
    atomicAdd(&gx[(size_t)cur * 128 + f], s);
  }

  if (!has_next) return;

  // H1p phase: Pout = relu(Xnew@W1e + b1e) (hi bf16) — W2e fused downstream
  floatx4 pacc[2][4];
#pragma unroll
  for (int mt = 0; mt < 2; ++mt)
#pragma unroll
    for (int nt = 0; nt < 4; ++nt) pacc[mt][nt] = zz;

#pragma unroll
  for (int kc = 0; kc < 4; ++kc) {
    const int cur = kc & 1, nxt = cur ^ 1;
    if (kc < 3) {
#pragma unroll
      for (int mt = 0; mt < 2; ++mt) {
        const bf16* wp = w1te + (size_t)(hbase + mt * 16 + lr) * 128 + (kc + 1) * 32 + q * 8;
        pah[nxt][mt] = *(const bf16x8*)wp;
        pal[nxt][mt] = *(const bf16x8*)(wp + 16384);
      }
    }
    bf16x8 bh[4], bl[4];
#pragma unroll
    for (int nt = 0; nt < 4; ++nt) {
      const float* xp = &Xt[(nt * 16 + lr) * 132 + kc * 32 + q * 8];
#pragma unroll
      for (int r = 0; r < 8; ++r) {
        const float v = xp[r];
        bh[nt][r] = (bf16)v;
        bl[nt][r] = (bf16)(v - (float)bh[nt][r]);
      }
    }
#pragma unroll
    for (int nt = 0; nt < 4; ++nt)
#pragma unroll
      for (int mt = 0; mt < 2; ++mt) {
        pacc[mt][nt] = MFMA(pah[cur][mt], bh[nt], pacc[mt][nt], 0, 0, 0);
        pacc[mt][nt] = MFMA(pal[cur][mt], bh[nt], pacc[mt][nt], 0, 0, 0);
        pacc[mt][nt] = MFMA(pah[cur][mt], bl[nt], pacc[mt][nt], 0, 0, 0);
      }
  }
  bar_lds();   // Xt reads (incl. gsum) done; H1p hi staging overlays R

  // epilogue: +b1e, relu -> hi bf16 stage, coalesced store
#pragma unroll
  for (int mt = 0; mt < 2; ++mt) {
    const int h0 = hbase + mt * 16 + q * 4;
    const float* bp = &b1e[h0];
#pragma unroll
    for (int nt = 0; nt < 4; ++nt) {
      const int e = nt * 16 + lr;
      bf16x4 hh;
#pragma unroll
      for (int r = 0; r < 4; ++r)
        hh[r] = (bf16)fmaxf(pacc[mt][nt][r] + bp[r], 0.f);
      *(bf16x4*)&R[e * 136 + h0] = hh;
    }
  }
  bar_lds();
#pragma unroll
  for (int it = 0; it < 4; ++it) {
    const int idx = it * 256 + tid;
    const int row = idx >> 4;
    const int f8 = (idx & 15) * 8;
    const int n = n0 + row;
    if (n < N)
      *(bf16x8*)&Pout[(size_t)n * 128 + f8] = *(const bf16x8*)&R[row * 136 + f8];
  }
}

// ---------------- UW = u @ W1c + b1 + b2e @ W1a (layer 0) ----------------
__global__ void uw_kernel(const float* __restrict__ u, const float* __restrict__ w1,
                          const float* __restrict__ b1, const float* __restrict__ pb,
                          float* __restrict__ UW) {
  const int b = blockIdx.x, h = threadIdx.x;
  float s = b1[h];
#pragma unroll 8
  for (int k = 0; k < 128; ++k)
    s = fmaf(u[b * 128 + k], w1[(size_t)(256 + k) * 128 + h], s);
#pragma unroll 8
  for (int k = 0; k < 128; ++k)
    s = fmaf(pb[k], w1[(size_t)(128 + k) * 128 + h], s);
  UW[b * 128 + h] = s;
}

// ---------------- standalone global MLP (last layer only) ----------------
__global__ __launch_bounds__(128)
void gmlp_kernel(const float* __restrict__ uin, float* __restrict__ gx,
                 const int* __restrict__ gcnt,
                 const float* __restrict__ gw1, const float* __restrict__ gb1,
                 const float* __restrict__ gw2, const float* __restrict__ gb2,
                 float* __restrict__ uout,
                 const float* __restrict__ w1n, const float* __restrict__ b1n,
                 const float* __restrict__ pbn, float* __restrict__ UW,
                 int has_next) {
  gmlp_dev(blockIdx.x, threadIdx.x, uin, gx, gcnt, gw1, gb1, gw2, gb2,
           uout, w1n, b1n, pbn, UW, has_next);
}

// ---------------- host ----------------
extern "C" void kernel_launch(void* const* d_in, const int* in_sizes, int n_in,
                              void* d_out, int out_size, void* d_ws, size_t ws_size,
                              hipStream_t stream) {
  constexpr int N = 50000, E = 600000, B = 64, F = 128, L = 4;

  const float* x0    = (const float*)d_in[0];
  const int*   ei    = (const int*)  d_in[1];
  const float* u0    = (const float*)d_in[2];
  const int*   batch = (const int*)  d_in[3];
  const float* n1w1  = (const float*)d_in[4];
  const float* n1b1  = (const float*)d_in[5];
  const float* n1w2  = (const float*)d_in[6];
  const float* n1b2  = (const float*)d_in[7];
  const float* n2w1  = (const float*)d_in[8];
  const float* n2b1  = (const float*)d_in[9];
  const float* n2w2  = (const float*)d_in[10];
  const float* n2b2  = (const float*)d_in[11];
  const float* gw1   = (const float*)d_in[12];
  const float* gb1   = (const float*)d_in[13];
  const float* gw2   = (const float*)d_in[14];
  const float* gb2   = (const float*)d_in[15];
  float* out = (float*)d_out;

  char* p = (char*)d_ws;
  auto carve = [&](size_t bytes) -> void* {
    void* q = (void*)p;
    p += (bytes + 255) & ~(size_t)255;
    return q;
  };
  float* ubuf  = (float*)carve((size_t)B * F * 4);
  float* gx    = (float*)carve((size_t)B * F * 4);
  float* UW    = (float*)carve((size_t)B * F * 4);
  int*   cnt   = (int*)carve((size_t)N * 4);
  int*   colptr= (int*)carve((size_t)(N + 1) * 4);
  int*   rctr  = (int*)carve((size_t)N * 4);
  int*   gcnt  = (int*)carve((size_t)B * 4);
  int*   btot  = (int*)carve(32 * 4);
  int*   esrow = (int*)carve((size_t)E * 4);
  bf16*  xhi   = (bf16*)carve((size_t)N * F * 2);
  bf16*  xlo   = (bf16*)carve((size_t)N * F * 2);
  bf16*  P_a   = (bf16*)carve((size_t)N * F * 2);
  bf16*  P_b   = (bf16*)carve((size_t)N * F * 2);
  bf16*  aggh  = (bf16*)carve((size_t)N * F * 2);
  bf16*  aggl  = (bf16*)carve((size_t)N * F * 2);
  bf16*  w1t_e = (bf16*)carve((size_t)L * 2 * 128 * 128 * 2);
  bf16*  w1t_n = (bf16*)carve((size_t)L * 2 * 256 * 128 * 2);
  bf16*  w2t_n = (bf16*)carve((size_t)L * 2 * 128 * 128 * 2);
  float* wtmp  = (float*)carve((size_t)L * 256 * 128 * 4);

  constexpr int SCAN_BLOCKS = (N + 2047) / 2048;

  hipMemsetAsync(cnt, 0, (size_t)N * 4, stream);
  hipMemsetAsync(gx, 0, (size_t)B * F * 4, stream);   // re-zeroed by gmlp
  hist_kernel<<<(E + 255) / 256, 256, 0, stream>>>(ei, cnt, E);
  gcnt_kernel<<<1, 64, 0, stream>>>(batch, gcnt, N, B);
  scan1_kernel<<<SCAN_BLOCKS, 256, 0, stream>>>(cnt, colptr, rctr, btot, N);
  scan2_kernel<<<SCAN_BLOCKS, 256, 0, stream>>>(colptr, rctr, btot, N);
  place_kernel<<<(E + 255) / 256, 256, 0, stream>>>(ei, rctr, esrow, E);
  wsplit_kernel<<<dim3(64, L), 256, 0, stream>>>(n1w1, w1t_e, 128, 128, 128);
  wfuse_kernel<<<dim3(128, L), 128, 0, stream>>>(n2w1, n1w2, wtmp);
  wsplit_kernel<<<dim3(128, L), 256, 0, stream>>>(wtmp, w1t_n, 256, 256, 128);
  wsplit_kernel<<<dim3(64, L), 256, 0, stream>>>(n2w2, w2t_n, 128, 128, 128);
  xsplit_kernel<<<(N * F / 4 + 255) / 256, 256, 0, stream>>>(x0, xhi, xlo, N * F / 4);
  uw_kernel<<<B, 128, 0, stream>>>(u0, n2w1, n2b1, n1b2, UW);

  const int NB = (N + 63) / 64;
  const int NAGG = (N + 7) / 8;   // 8 columns per block (2 per wave)
  pnode_mfma<<<NB, 256, 0, stream>>>(xhi, xlo, w1t_e, n1b1, P_a, N);

  // layer-0 aggregate (no gmlp blocks: grid == NAGG)
  agg_csr<<<NAGG, 256, 0, stream>>>(P_a, colptr, esrow, aggh, aggl, N, E, NAGG,
      u0, gx, gcnt, gw1, gb1, gw2, gb2, ubuf, n2w1, n2b1, n1b2, UW);

  for (int l = 0; l < L; ++l) {
    const int    wx   = (l == L - 1) ? 1 : 0;
    const int    hn   = (l < L - 1) ? 1 : 0;
    bf16*        Pout = (l & 1) ? P_a : P_b;
    const int    le   = hn ? (l + 1) : l;

    node_p<<<NB, 256, 0, stream>>>(
        xhi, xlo, aggh, aggl, UW, batch,
        w1t_n + (size_t)l * 65536, w2t_n + (size_t)l * 32768,
        n2b2 + l * 128,
        w1t_e + (size_t)le * 32768, n1b1 + le * 128,
        Pout, gx, out, wx, hn, N);

    if (l < L - 1) {
      // aggregate for layer l+1, with this layer's gmlp fused in as B blocks
      agg_csr<<<NAGG + B, 256, 0, stream>>>(
          Pout, colptr, esrow, aggh, aggl, N, E, NAGG,
          (l ? ubuf : u0), gx, gcnt,
          gw1 + (size_t)l * 256 * 128, gb1 + l * 128,
          gw2 + (size_t)l * 128 * 128, gb2 + l * 128,
          ubuf,
          n2w1 + (size_t)(l + 1) * 384 * 128, n2b1 + (l + 1) * 128,
          n1b2 + (l + 1) * 128, UW);
    } else {
      gmlp_kernel<<<B, 128, 0, stream>>>(
          ubuf, gx, gcnt,
          gw1 + (size_t)l * 256 * 128, gb1 + l * 128,
          gw2 + (size_t)l * 128 * 128, gb2 + l * 128,
          out + (size_t)N * F,
          n2w1, n2b1, n1b2, UW, 0);
    }
  }
}